// Round 2
// baseline (559.701 us; speedup 1.0000x reference)
//
#include <hip/hip_runtime.h>
#include <hip/hip_bf16.h>
#include <stdint.h>

#define BB 2
#define SS 4096
#define HH 1024
#define NHh 16
#define HD 64
#define LL 64
#define BS 64
#define RR 3
#define PENf (-10000.0f)

typedef unsigned int uint;
typedef __attribute__((ext_vector_type(8))) short bf16x8;
typedef __attribute__((ext_vector_type(4))) float f32x4;

__device__ __forceinline__ ushort f2bf(float f) {
    union { float f; uint u; } v; v.f = f;
    uint u = v.u;
    return (ushort)((u + 0x7fffu + ((u >> 16) & 1u)) >> 16);  // RNE
}
// packed f32x2 -> bf16x2 via HW cvt (RNE), 1 instr instead of ~10 VALU ops
__device__ __forceinline__ uint pack_bf(float a, float b) {
    uint r;
    asm("v_cvt_pk_bf16_f32 %0, %1, %2" : "=v"(r) : "v"(a), "v"(b));
    return r;
}
// scale both bf16 halves of a packed uint by 0.125 (exact, pow2)
__device__ __forceinline__ uint scale_pair(uint w) {
    float lo = __uint_as_float(w << 16) * 0.125f;
    float hi = __uint_as_float(w & 0xffff0000u) * 0.125f;
    return pack_bf(lo, hi);
}
__device__ __forceinline__ uint4 scale4(uint4 w) {
    uint4 o;
    o.x = scale_pair(w.x); o.y = scale_pair(w.y);
    o.z = scale_pair(w.z); o.w = scale_pair(w.w);
    return o;
}
// async global->LDS, 16B per lane; lds base must be wave-uniform (lane*16 auto)
__device__ __forceinline__ void async16(const ushort* g, ushort* l) {
    __builtin_amdgcn_global_load_lds((const __attribute__((address_space(1))) uint*)g,
                                     (__attribute__((address_space(3))) uint*)l,
                                     16, 0, 0);
}

// ---------------- fp32 -> bf16 convert (X and W), exact grid ----------------
// grid = 13824 blocks x 256: 12288 X-blocks then 1536 W-blocks (uniform branch).
__global__ __launch_bounds__(256)
void cvt_kernel(const float* __restrict__ Xq, const float* __restrict__ Xk,
                const float* __restrict__ Xv, const float* __restrict__ Wq,
                const float* __restrict__ Wk, const float* __restrict__ Wv,
                ushort* __restrict__ Xbf, ushort* __restrict__ Wbf)
{
    const size_t XTOT = (size_t)3 * BB * SS * HH;   // 25165824 = 3 * 2^23
    const uint u = blockIdx.x * 256 + threadIdx.x;
    const size_t e = (size_t)u * 8;
    const float* src; ushort* dst;
    if (e < XTOT) {
        const int zz = (int)(e >> 23);
        src = (zz == 0 ? Xq : zz == 1 ? Xk : Xv) + (e & ((1u << 23) - 1));
        dst = Xbf + e;
    } else {
        const size_t e2 = e - XTOT;
        const int zz = (int)(e2 >> 20);
        src = (zz == 0 ? Wq : zz == 1 ? Wk : Wv) + (e2 & ((1u << 20) - 1));
        dst = Wbf + e2;
    }
    float4 a = ((const float4*)src)[0];
    float4 c = ((const float4*)src)[1];
    uint4 o;
    o.x = pack_bf(a.x, a.y); o.y = pack_bf(a.z, a.w);
    o.z = pack_bf(c.x, c.y); o.w = pack_bf(c.z, c.w);
    *(uint4*)dst = o;
}

// ---------------- 256x256 bf16 GEMM, counted-vmcnt deep pipeline ----------------
// C[m][n] = sum_k A[m][k]*Bt[n][k] + bias[n]; A bf16 [8192][1024], Bt bf16 [1024][1024].
// BK=32, 4 LDS K-tile buffers, depth-3 prefetch, vmcnt(8) steady state (never 0),
// raw s_barrier per tile, setprio around MFMA cluster, XOR slot swizzle (2-way/free).
// z=0 -> qb [bh][s][hd], z=1 -> kb, z=2 -> vbT [bh][hd][s].
__global__ __launch_bounds__(512, 2)
void gemm8_kernel(const ushort* __restrict__ Xbf, const ushort* __restrict__ Wbf,
                  const float* __restrict__ bq, const float* __restrict__ bk,
                  const float* __restrict__ bv,
                  ushort* __restrict__ qb, ushort* __restrict__ kb,
                  ushort* __restrict__ vbT)
{
    // 4 x (A 256x32 + B 256x32) bf16 = 128 KiB
    __shared__ __align__(16) ushort smem8[65536];
    ushort* As_ = smem8;            // [4][256*32], swizzled slots
    ushort* Bs_ = smem8 + 32768;

    const int z = blockIdx.z;
    const ushort* Ag = Xbf + (size_t)z * ((size_t)BB * SS * HH);
    const ushort* Bg = Wbf + (size_t)z * (HH * HH);
    const float* bias = (z == 0) ? bq : (z == 1) ? bk : bv;
    const bool zv = (z == 2);

    const int tid = threadIdx.x;
    const int m0 = blockIdx.x * 256;
    const int n0 = blockIdx.y * 256;
    const int wave = tid >> 6;
    const int lane = tid & 63;
    const int l15 = lane & 15;
    const int quad = lane >> 4;
    const int wr = wave >> 2;      // 0..1 : m-half (128 rows)
    const int wc = wave & 3;       // 0..3 : n-quarter (64 rows)

    f32x4 acc[8][4];
#pragma unroll
    for (int mi = 0; mi < 8; ++mi)
#pragma unroll
        for (int ni = 0; ni < 4; ++ni) acc[mi][ni] = (f32x4){0.f, 0.f, 0.f, 0.f};

    // staging: thread t -> row t>>2 (+128 for 2nd load), phys slot t&3 holds
    // logical k-slot (t&3)^((row>>1)&3); same involution on the read side.
    const int trow = tid >> 2;
    const int tcol = ((tid & 3) ^ ((tid >> 3) & 3)) * 8;
    const ushort* Ath = Ag + (size_t)(m0 + trow) * HH + tcol;
    const ushort* Bth = Bg + (size_t)(n0 + trow) * HH + tcol;
    // read-side swizzled slot (row>>1)&3 == (l15>>1)&3 for all frag rows
    const int sl8 = (quad ^ ((l15 >> 1) & 3)) * 8;

#define STAGE8(kt_)                                                   \
    do {                                                              \
        const int k0_ = (kt_) * 32;                                   \
        const int sb_ = ((kt_) & 3) * 8192 + wave * 512;              \
        async16(Ath + k0_,            As_ + sb_);                     \
        async16(Ath + 128 * HH + k0_, As_ + sb_ + 4096);              \
        async16(Bth + k0_,            Bs_ + sb_);                     \
        async16(Bth + 128 * HH + k0_, Bs_ + sb_ + 4096);              \
    } while (0)

#define TILE_BODY(kt_, VM_, DOSTAGE_)                                              \
    do {                                                                           \
        const int bp_ = (kt_) & 3;                                                 \
        asm volatile("s_waitcnt vmcnt(" #VM_ ")" ::: "memory");                    \
        __builtin_amdgcn_s_barrier();                                              \
        __builtin_amdgcn_sched_barrier(0);                                         \
        const ushort* Ab_ = As_ + bp_ * 8192;                                      \
        const ushort* Bb_ = Bs_ + bp_ * 8192;                                      \
        bf16x8 af_[8], bf_[4];                                                     \
        _Pragma("unroll")                                                          \
        for (int ni = 0; ni < 4; ++ni)                                             \
            bf_[ni] = *(const bf16x8*)(Bb_ + (wc * 64 + ni * 16 + l15) * 32 + sl8);\
        _Pragma("unroll")                                                          \
        for (int mi = 0; mi < 8; ++mi)                                             \
            af_[mi] = *(const bf16x8*)(Ab_ + (wr * 128 + mi * 16 + l15) * 32 + sl8);\
        if (DOSTAGE_) STAGE8((kt_) + 3);                                           \
        __builtin_amdgcn_s_setprio(1);                                             \
        if (zv) {                                                                  \
            _Pragma("unroll")                                                      \
            for (int mi = 0; mi < 8; ++mi)                                         \
                _Pragma("unroll")                                                  \
                for (int ni = 0; ni < 4; ++ni)                                     \
                    acc[mi][ni] = __builtin_amdgcn_mfma_f32_16x16x32_bf16(         \
                        af_[mi], bf_[ni], acc[mi][ni], 0, 0, 0);                   \
        } else {                                                                   \
            _Pragma("unroll")                                                      \
            for (int mi = 0; mi < 8; ++mi)                                         \
                _Pragma("unroll")                                                  \
                for (int ni = 0; ni < 4; ++ni)                                     \
                    acc[mi][ni] = __builtin_amdgcn_mfma_f32_16x16x32_bf16(         \
                        bf_[ni], af_[mi], acc[mi][ni], 0, 0, 0);                   \
        }                                                                          \
        __builtin_amdgcn_s_setprio(0);                                             \
    } while (0)

    STAGE8(0); STAGE8(1); STAGE8(2);          // 12 loads in flight

    for (int k4 = 0; k4 < 28; k4 += 4) {      // kt = 0..27, all stage kt+3
        TILE_BODY(k4 + 0, 8, 1);
        TILE_BODY(k4 + 1, 8, 1);
        TILE_BODY(k4 + 2, 8, 1);
        TILE_BODY(k4 + 3, 8, 1);
    }
    TILE_BODY(28, 8, 1);                      // stages tile 31
    TILE_BODY(29, 8, 0);
    TILE_BODY(30, 4, 0);
    TILE_BODY(31, 0, 0);
#undef TILE_BODY
#undef STAGE8

    if (!zv) {
        // acc[mi][ni]: D row = n-local (wc*64+ni*16+quad*4+rr), col = m-local (wr*128+mi*16+l15)
        ushort* outp = (z == 0) ? qb : kb;
#pragma unroll
        for (int ni = 0; ni < 4; ++ni) {
            const int nb = n0 + wc * 64 + ni * 16 + quad * 4;   // 4 consecutive n (hd)
            const float4 b4 = *(const float4*)&bias[nb];
            const int nh = nb >> 6;
            const int hd = nb & 63;
#pragma unroll
            for (int mi = 0; mi < 8; ++mi) {
                const int m = m0 + wr * 128 + mi * 16 + l15;
                const int bgl = m >> 12, s = m & 4095;
                uint2 pk;
                pk.x = pack_bf(acc[mi][ni][0] + b4.x, acc[mi][ni][1] + b4.y);
                pk.y = pack_bf(acc[mi][ni][2] + b4.z, acc[mi][ni][3] + b4.w);
                *(uint2*)&outp[((size_t)((bgl << 4) | nh) * SS + s) * HD + hd] = pk;
            }
        }
    } else {
        // V: acc[mi][ni]: D row = m-local (quad*4+rr), col = n-local (l15).
        // restage transposed in LDS (two 128-n passes), coalesced store to vbT [bh][hd][s]
        __syncthreads();
        ushort* stg = smem8;   // [128 n][272 m]
        const int bgl = m0 >> 12;
#pragma unroll
        for (int p = 0; p < 2; ++p) {
            __syncthreads();
            if ((wc >> 1) == p) {
#pragma unroll
                for (int ni = 0; ni < 4; ++ni) {
                    const int nl = (wc & 1) * 64 + ni * 16 + l15;
                    const float bn = bias[n0 + p * 128 + nl];
#pragma unroll
                    for (int mi = 0; mi < 8; ++mi) {
                        const int mb = wr * 128 + mi * 16 + quad * 4;
                        uint2 pk;
                        pk.x = pack_bf(acc[mi][ni][0] + bn, acc[mi][ni][1] + bn);
                        pk.y = pack_bf(acc[mi][ni][2] + bn, acc[mi][ni][3] + bn);
                        *(uint2*)(stg + nl * 272 + mb) = pk;
                    }
                }
            }
            __syncthreads();
            {
                const int row = tid >> 2;      // 0..127
                const int seg = tid & 3;       // 64-m segment
                const int n = n0 + p * 128 + row;
                const int nh = n >> 6, hd = n & 63;
                const uint4* src = (const uint4*)(stg + row * 272 + seg * 64);
                uint4* dst = (uint4*)(vbT + ((size_t)((bgl << 4) | nh) * HD + hd) * SS
                                      + (m0 & 4095) + seg * 64);
#pragma unroll
                for (int jj = 0; jj < 8; ++jj) dst[jj] = src[jj];
            }
        }
    }
}

// ---------------- R1 fallback projection (inline convert) ----------------
__global__ __launch_bounds__(256)
void proj3_kernel(const float* __restrict__ Xq, const float* __restrict__ Xk,
                  const float* __restrict__ Xv,
                  const float* __restrict__ Wq, const float* __restrict__ Wk,
                  const float* __restrict__ Wv,
                  const float* __restrict__ bq, const float* __restrict__ bk,
                  const float* __restrict__ bv,
                  ushort* __restrict__ qb, ushort* __restrict__ kb,
                  ushort* __restrict__ vbT)
{
    __shared__ __align__(16) ushort smem[128 * 136];
    ushort* As = smem;             // [128][40]
    ushort* Bs = smem + 128 * 40;  // [128][40]

    const int z = blockIdx.z;
    const float* X    = (z == 0) ? Xq : (z == 1) ? Xk : Xv;
    const float* W    = (z == 0) ? Wq : (z == 1) ? Wk : Wv;
    const float* bias = (z == 0) ? bq : (z == 1) ? bk : bv;

    const int tid = threadIdx.x;
    const int m0 = blockIdx.x * 128;
    const int n0 = blockIdx.y * 128;
    const int wave = tid >> 6;
    const int lane = tid & 63;
    const int l15 = lane & 15;
    const int quad = lane >> 4;
    const int wr = wave >> 1, wc = wave & 1;

    f32x4 acc[4][4];
#pragma unroll
    for (int mt = 0; mt < 4; ++mt)
#pragma unroll
        for (int nt = 0; nt < 4; ++nt) acc[mt][nt] = (f32x4){0.f, 0.f, 0.f, 0.f};

    const int srow = tid >> 1;
    const int shalf = tid & 1;
    const float* xp = X + (size_t)(m0 + srow) * HH + shalf * 16;
    const float* wp = W + (size_t)(n0 + srow) * HH + shalf * 16;
    ushort* asw = As + srow * 40 + shalf * 16;
    ushort* bsw = Bs + srow * 40 + shalf * 16;

    for (int k0 = 0; k0 < HH; k0 += 32) {
        float4 a0 = *(const float4*)(xp + k0);
        float4 a1 = *(const float4*)(xp + k0 + 4);
        float4 a2 = *(const float4*)(xp + k0 + 8);
        float4 a3 = *(const float4*)(xp + k0 + 12);
        float4 b0 = *(const float4*)(wp + k0);
        float4 b1 = *(const float4*)(wp + k0 + 4);
        float4 b2 = *(const float4*)(wp + k0 + 8);
        float4 b3 = *(const float4*)(wp + k0 + 12);
        __syncthreads();
        uint4 pa, pb;
        pa.x = pack_bf(a0.x, a0.y); pa.y = pack_bf(a0.z, a0.w);
        pa.z = pack_bf(a1.x, a1.y); pa.w = pack_bf(a1.z, a1.w);
        *(uint4*)asw = pa;
        pa.x = pack_bf(a2.x, a2.y); pa.y = pack_bf(a2.z, a2.w);
        pa.z = pack_bf(a3.x, a3.y); pa.w = pack_bf(a3.z, a3.w);
        *(uint4*)(asw + 8) = pa;
        pb.x = pack_bf(b0.x, b0.y); pb.y = pack_bf(b0.z, b0.w);
        pb.z = pack_bf(b1.x, b1.y); pb.w = pack_bf(b1.z, b1.w);
        *(uint4*)bsw = pb;
        pb.x = pack_bf(b2.x, b2.y); pb.y = pack_bf(b2.z, b2.w);
        pb.z = pack_bf(b3.x, b3.y); pb.w = pack_bf(b3.z, b3.w);
        *(uint4*)(bsw + 8) = pb;
        __syncthreads();

        bf16x8 af[4], bfr[4];
#pragma unroll
        for (int mt = 0; mt < 4; ++mt)
            af[mt] = *(const bf16x8*)(As + (wr * 64 + mt * 16 + l15) * 40 + quad * 8);
#pragma unroll
        for (int nt = 0; nt < 4; ++nt)
            bfr[nt] = *(const bf16x8*)(Bs + (wc * 64 + nt * 16 + l15) * 40 + quad * 8);
#pragma unroll
        for (int mt = 0; mt < 4; ++mt)
#pragma unroll
            for (int nt = 0; nt < 4; ++nt)
                acc[mt][nt] = __builtin_amdgcn_mfma_f32_16x16x32_bf16(af[mt], bfr[nt], acc[mt][nt], 0, 0, 0);
    }

    if (z < 2) {
        ushort* outp = (z == 0) ? qb : kb;
#pragma unroll
        for (int nt = 0; nt < 4; ++nt) {
            const int n = n0 + wc * 64 + nt * 16 + l15;
            const float bn = bias[n];
            const int nh = n >> 6, hd = n & 63;
#pragma unroll
            for (int mt = 0; mt < 4; ++mt) {
#pragma unroll
                for (int rr = 0; rr < 4; ++rr) {
                    const int m = m0 + wr * 64 + mt * 16 + quad * 4 + rr;
                    const int bgl = m >> 12, s = m & 4095;
                    outp[((size_t)((bgl << 4) | nh) * SS + s) * HD + hd] = f2bf(acc[mt][nt][rr] + bn);
                }
            }
        }
    } else {
        __syncthreads();
        ushort* stg = smem;
#pragma unroll
        for (int nt = 0; nt < 4; ++nt) {
            const int n_local = wc * 64 + nt * 16 + l15;
            const float bn = bias[n0 + n_local];
#pragma unroll
            for (int mt = 0; mt < 4; ++mt) {
                const int m_base = wr * 64 + mt * 16 + quad * 4;
                uint2 pk;
                pk.x = pack_bf(acc[mt][nt][0] + bn, acc[mt][nt][1] + bn);
                pk.y = pack_bf(acc[mt][nt][2] + bn, acc[mt][nt][3] + bn);
                *(uint2*)(stg + n_local * 136 + m_base) = pk;
            }
        }
        __syncthreads();
        const int n_row = tid >> 1;
        const int half = tid & 1;
        const int n = n0 + n_row;
        const int nh = n >> 6, hd = n & 63;
        const int bgl = m0 >> 12;
        const int sbase = (m0 & 4095) + half * 64;
        const uint4* src = (const uint4*)(stg + n_row * 136 + half * 64);
        uint4* dst = (uint4*)(vbT + ((size_t)((bgl << 4) | nh) * HD + hd) * SS + sbase);
#pragma unroll
        for (int j = 0; j < 8; ++j) dst[j] = src[j];
    }
}

// ---------------- block-sparse attention, S^T + dbuf single-barrier ----------------
// qg/kg bf16 [bh][s][d]; vTg bf16 [bh][d][s]; out f32 [b][s][h*d].
// K/V LDS tiles use an XOR column swizzle (slot ^= (row>>1)&3) applied BOTH at the
// global source of global_load_lds (linear LDS dest) and at the ds_read side.
__global__ __launch_bounds__(256)
void attn_kernel(const ushort* __restrict__ qg, const ushort* __restrict__ kg,
                 const ushort* __restrict__ vTg,
                 const float* __restrict__ mask, const int* __restrict__ rand_attn,
                 float* __restrict__ out, float* __restrict__ partO,
                 float* __restrict__ partML)
{
    __shared__ __align__(16) ushort qs_ps[64][72];      // q staging, then ps (wave-private bands)
    __shared__ __align__(16) ushort ks2[2][2][64][32];  // [buf][k-chunk][kc][d32] (col-swizzled)
    __shared__ __align__(16) ushort vs2[2][2][64][32];  // [buf][kc-chunk][d][kc32] (col-swizzled)
    __shared__ __align__(16) float qm_s[64];
    __shared__ __align__(16) float km_s[2][64];

    const int tid = threadIdx.x;
    const int wid = blockIdx.x;
    const int bh = wid / 78;
    const int r = wid - bh * 78;
    const int b = bh >> 4, h = bh & 15;

    int i, nkb;
    int kbl[8], pfl[8];
    bool dense;
    int part = 0, which = 0;
    if (r < 62) {
        dense = false;
        i = r + 1;
        const int* ra = rand_attn + ((size_t)h * (LL - 2) + (i - 1)) * RR;
        if (i == 1) {
            kbl[0] = 0; kbl[1] = 1; kbl[2] = 2; kbl[3] = LL - 1;
            kbl[4] = ra[0]; kbl[5] = ra[1]; kbl[6] = ra[2]; kbl[7] = 0;
            pfl[0] = pfl[1] = pfl[2] = pfl[3] = 0;
            pfl[4] = pfl[5] = pfl[6] = 1; pfl[7] = 0;
            nkb = 7;
        } else if (i == LL - 2) {
            kbl[0] = 0; kbl[1] = LL - 3; kbl[2] = LL - 2; kbl[3] = LL - 1;
            kbl[4] = ra[0]; kbl[5] = ra[1]; kbl[6] = ra[2]; kbl[7] = 0;
            pfl[0] = pfl[1] = pfl[2] = pfl[3] = 0;
            pfl[4] = pfl[5] = pfl[6] = 1; pfl[7] = 0;
            nkb = 7;
        } else {
            kbl[0] = 0;      pfl[0] = 0;
            kbl[1] = i - 1;  pfl[1] = 1;
            kbl[2] = i;      pfl[2] = 1;
            kbl[3] = i + 1;  pfl[3] = 1;
            kbl[4] = LL - 1; pfl[4] = 0;
            kbl[5] = ra[0]; kbl[6] = ra[1]; kbl[7] = ra[2];
            pfl[5] = pfl[6] = pfl[7] = 1;
            nkb = 8;
        }
    } else {
        dense = true;
        const int r2 = r - 62;
        which = r2 >> 3;
        part = r2 & 7;
        i = which ? (LL - 1) : 0;
        nkb = 8;
#pragma unroll
        for (int j = 0; j < 8; ++j) { kbl[j] = part * 8 + j; pfl[j] = 0; }
    }

    const int lane = tid & 63;
    const int wave = tid >> 6;
    const int l15 = lane & 15;
    const int quad = lane >> 4;
    const int srow = lane >> 2;
    // swizzled 16B-slot for K/V staging: slot ^= (row_in_16 >> 1) & 3
    const int p8s = (((lane & 3) ^ ((srow >> 1) & 3))) * 8;
    const ushort* kgb = kg + (size_t)bh * SS * HD;
    const ushort* vgb = vTg + (size_t)bh * HD * SS;

#define STAGE_KV(kb_, bp)                                                        \
    do {                                                                         \
        const size_t krow = (size_t)((kb_) * BS + wave * 16 + srow) * HD;        \
        async16(kgb + krow + p8s,      &ks2[bp][0][wave * 16][0]);               \
        async16(kgb + krow + 32 + p8s, &ks2[bp][1][wave * 16][0]);               \
        const size_t vrow = (size_t)(wave * 16 + srow) * SS + (kb_) * BS;        \
        async16(vgb + vrow + p8s,      &vs2[bp][0][wave * 16][0]);               \
        async16(vgb + vrow + 32 + p8s, &vs2[bp][1][wave * 16][0]);               \
    } while (0)

    // stage q (scaled by rsd) + masks + first K/V buffer
    {
        const int row = tid >> 2;
        const int c0 = (tid & 3) * 16;
        const ushort* src = qg + ((size_t)bh * SS + i * BS + row) * HD + c0;
        uint4 w0 = *(const uint4*)src;
        uint4 w1 = *(const uint4*)(src + 8);
        *(uint4*)&qs_ps[row][c0] = scale4(w0);
        *(uint4*)&qs_ps[row][c0 + 8] = scale4(w1);
        if (tid < 64) qm_s[tid] = mask[(size_t)b * SS + i * BS + tid];
    }
    STAGE_KV(kbl[0], 0);
    if (tid < 64) km_s[0][tid] = mask[(size_t)b * SS + kbl[0] * BS + tid];
    __syncthreads();  // publish qs, buf0, masks

    // hoist q fragments (B-operand, n=q=wave*16+l15); qs region becomes ps after this
    bf16x8 aq[2];
    aq[0] = *(const bf16x8*)&qs_ps[wave * 16 + l15][quad * 8];
    aq[1] = *(const bf16x8*)&qs_ps[wave * 16 + l15][32 + quad * 8];
    const float qm = qm_s[wave * 16 + l15];

    // swizzled read slot for K/V tiles (same involution as p8s, row_in_16 = l15)
    const int sqz = (quad ^ ((l15 >> 1) & 3)) * 8;

    float mrow = -1e30f, lrow = 0.0f;   // per-lane, q = wave*16 + l15
    f32x4 accO[4];
#pragma unroll
    for (int dt = 0; dt < 4; ++dt) accO[dt] = (f32x4){0.f, 0.f, 0.f, 0.f};

    for (int it = 0; it < nkb; ++it) {
        const int cur = it & 1;
        if (it + 1 < nkb) {
            STAGE_KV(kbl[it + 1], cur ^ 1);   // flies during this iter's compute
            if (tid < 64) km_s[cur ^ 1][tid] = mask[(size_t)b * SS + kbl[it + 1] * BS + tid];
        }
        const int pf = pfl[it];

        // S^T = K . Q^T : A = K rows (m=kc), B = Q rows (n=q)
        f32x4 sc[4];
#pragma unroll
        for (int nt = 0; nt < 4; ++nt) sc[nt] = (f32x4){0.f, 0.f, 0.f, 0.f};
#pragma unroll
        for (int c = 0; c < 2; ++c) {
#pragma unroll
            for (int nt = 0; nt < 4; ++nt) {
                bf16x8 af = *(const bf16x8*)&ks2[cur][c][nt * 16 + l15][sqz];
                sc[nt] = __builtin_amdgcn_mfma_f32_16x16x32_bf16(af, aq[c], sc[nt], 0, 0, 0);
            }
        }

        // penalties: lane holds (q = wave*16+l15, kc = nt*16+quad*4+rr)
        float p[4][4];
        float bm = -1e30f;
#pragma unroll
        for (int nt = 0; nt < 4; ++nt) {
            const float4 km4 = *(const float4*)&km_s[cur][nt * 16 + quad * 4];
            const float kmv[4] = {km4.x, km4.y, km4.z, km4.w};
#pragma unroll
            for (int rr = 0; rr < 4; ++rr) {
                const float pm = pf ? (qm * kmv[rr]) : kmv[rr];
                const float sv = sc[nt][rr] + (1.0f - pm) * PENf;
                p[nt][rr] = sv;
                bm = fmaxf(bm, sv);
            }
        }
        bm = fmaxf(bm, __shfl_xor(bm, 16));
        bm = fmaxf(bm, __shfl_xor(bm, 32));
        // defer-max (T13): only rescale when some row's max grew by > 8
        if (!__all(bm - mrow <= 8.0f)) {
            const float mn = fmaxf(mrow, bm);
            const float alpha = __expf(mrow - mn);
            mrow = mn;
            float a4[4];
#pragma unroll
            for (int rr = 0; rr < 4; ++rr) a4[rr] = __shfl(alpha, quad * 4 + rr, 64);
#pragma unroll
            for (int dt = 0; dt < 4; ++dt) {
#pragma unroll
                for (int rr = 0; rr < 4; ++rr) accO[dt][rr] *= a4[rr];
            }
            lrow *= alpha;
        }
        float ls = 0.0f;
#pragma unroll
        for (int nt = 0; nt < 4; ++nt)
#pragma unroll
            for (int rr = 0; rr < 4; ++rr) {
                p[nt][rr] = __expf(p[nt][rr] - mrow);   // bounded by e^8 when deferred
                ls += p[nt][rr];
            }
        ls += __shfl_xor(ls, 16);
        ls += __shfl_xor(ls, 32);
        lrow += ls;

        // write P (bf16) into wave-private ps rows; b64 stores
#pragma unroll
        for (int nt = 0; nt < 4; ++nt) {
            uint2 pk;
            pk.x = pack_bf(p[nt][0], p[nt][1]);
            pk.y = pack_bf(p[nt][2], p[nt][3]);
            *(uint2*)&qs_ps[wave * 16 + l15][nt * 16 + quad * 4] = pk;
        }

        // PV: A = ps (m=q), B = vs2 (n=d); ps is wave-private -> no barrier
#pragma unroll
        for (int c = 0; c < 2; ++c) {
            bf16x8 ap = *(const bf16x8*)&qs_ps[wave * 16 + l15][c * 32 + quad * 8];
#pragma unroll
            for (int dt = 0; dt < 4; ++dt) {
                bf16x8 bvf = *(const bf16x8*)&vs2[cur][c][dt * 16 + l15][sqz];
                accO[dt] = __builtin_amdgcn_mfma_f32_16x16x32_bf16(ap, bvf, accO[dt], 0, 0, 0);
            }
        }

        if (it + 1 < nkb) __syncthreads();  // publish buf cur^1; protect buf reuse
    }
#undef STAGE_KV

    if (!dense) {
#pragma unroll
        for (int rr = 0; rr < 4; ++rr) {
            const int qloc = quad * 4 + rr;
            const float lq = __shfl(lrow, qloc, 64);
            const float inv = qm_s[wave * 16 + qloc] / lq;
#pragma unroll
            for (int dt = 0; dt < 4; ++dt) {
                const int d = dt * 16 + l15;
                out[((size_t)b * SS + i * BS + wave * 16 + qloc) * HH + h * HD + d] = accO[dt][rr] * inv;
            }
        }
    } else {
        const int slot = (bh * 2 + which) * 8 + part;
        float* po = partO + (size_t)slot * 4096;
#pragma unroll
        for (int rr = 0; rr < 4; ++rr) {
            const int qrow = wave * 16 + quad * 4 + rr;
#pragma unroll
            for (int dt = 0; dt < 4; ++dt) {
                const int d = dt * 16 + l15;
                po[qrow * 64 + d] = accO[dt][rr];
            }
        }
        if (lane < 16) {
            partML[slot * 128 + wave * 16 + lane] = mrow;
            partML[slot * 128 + 64 + wave * 16 + lane] = lrow;
        }
    }
}

// ---------------- combine partials for dense query blocks ----------------
// 256 blocks x 64 threads -> engage all CUs; latency-bound.
__global__ __launch_bounds__(64)
void combine_kernel(const float* __restrict__ partO, const float* __restrict__ partML,
                    const float* __restrict__ mask, float* __restrict__ out)
{
    const int g4 = blockIdx.x;    // (bh*2 + which) * 4 + row-quarter
    const int g = g4 >> 2;
    const int bh = g >> 1, which = g & 1;
    const int b = bh >> 4, h = bh & 15;
    const int i = which ? (LL - 1) : 0;
    const int t = threadIdx.x;
    const int row = ((g4 & 3) << 4) | (t >> 2);
    const int d0 = (t & 3) * 16;
    const int base = g * 8;

    float mp[8], lp[8];
    float M = -1e30f;
#pragma unroll
    for (int p = 0; p < 8; ++p) {
        mp[p] = partML[(base + p) * 128 + row];
        lp[p] = partML[(base + p) * 128 + 64 + row];
        M = fmaxf(M, mp[p]);
    }
    float L = 0.0f, w[8];
#pragma unroll
    for (int p = 0; p < 8; ++p) { w[p] = __expf(mp[p] - M); L += lp[p] * w[p]; }

    float4 o[4];
#pragma unroll
    for (int j = 0; j < 4; ++j) o[j] = make_float4(0.f, 0.f, 0.f, 0.f);
#pragma unroll
    for (int p = 0; p < 8; ++p) {
        const float* po = partO + (size_t)(base + p) * 4096 + row * 64 + d0;
#pragma unroll
        for (int j = 0; j < 4; ++j) {
            float4 v = *(const float4*)(po + j * 4);
            o[j].x = fmaf(w[p], v.x, o[j].x);
            o[j].y = fmaf(w[p], v.y, o[j].y);
            o[j].z = fmaf(w[p], v.z, o[j].z);
            o[j].w = fmaf(w[p], v.w, o[j].w);
        }
    }
    const float fm = mask[(size_t)b * SS + i * BS + row];
    const float inv = fm / L;
    float* dst = out + ((size_t)b * SS + i * BS + row) * HH + h * HD + d0;
#pragma unroll
    for (int j = 0; j < 4; ++j) {
        float4 v;
        v.x = o[j].x * inv; v.y = o[j].y * inv;
        v.z = o[j].z * inv; v.w = o[j].w * inv;
        *(float4*)(dst + j * 4) = v;
    }
}

extern "C" void kernel_launch(void* const* d_in, const int* in_sizes, int n_in,
                              void* d_out, int out_size, void* d_ws, size_t ws_size,
                              hipStream_t stream) {
    (void)in_sizes; (void)n_in; (void)out_size;
    const float* Q    = (const float*)d_in[0];
    const float* K    = (const float*)d_in[1];
    const float* V    = (const float*)d_in[2];
    const float* mask = (const float*)d_in[3];
    const float* Wq   = (const float*)d_in[4];
    const float* bq   = (const float*)d_in[5];
    const float* Wk   = (const float*)d_in[6];
    const float* bk   = (const float*)d_in[7];
    const float* Wv   = (const float*)d_in[8];
    const float* bv   = (const float*)d_in[9];
    const int*   ra   = (const int*)d_in[10];
    float* out = (float*)d_out;

    const size_t qkv = (size_t)BB * NHh * SS * HD;  // 8388608 elems
    ushort* qb  = (ushort*)d_ws;
    ushort* kb  = qb + qkv;
    ushort* vbT = kb + qkv;
    float* partO  = (float*)(vbT + qkv);            // 512 * 4096 f32
    float* partML = partO + (size_t)512 * 4096;     // 512 * 128 f32
    ushort* Xbf = (ushort*)(partML + (size_t)512 * 128);
    ushort* Wbf = Xbf + 3 * qkv;
    const size_t need = (size_t)((char*)(Wbf + (size_t)3 * HH * HH) - (char*)d_ws);

    if (ws_size >= need) {
        cvt_kernel<<<13824, 256, 0, stream>>>(Q, K, V, Wq, Wk, Wv, Xbf, Wbf);
        gemm8_kernel<<<dim3(32, 4, 3), 512, 0, stream>>>(Xbf, Wbf, bq, bk, bv, qb, kb, vbT);
    } else {
        proj3_kernel<<<dim3(64, 8, 3), 256, 0, stream>>>(Q, K, V, Wq, Wk, Wv, bq, bk, bv,
                                                         qb, kb, vbT);
    }
    attn_kernel<<<dim3(BB * NHh * 78), 256, 0, stream>>>(qb, kb, vbT, mask, ra,
                                                         out, partO, partML);
    combine_kernel<<<dim3(BB * NHh * 2 * 4), 64, 0, stream>>>(partO, partML, mask, out);
}

// Round 3
// 559.262 us; speedup vs baseline: 1.0008x; 1.0008x over previous
//
#include <hip/hip_runtime.h>
#include <hip/hip_bf16.h>
#include <stdint.h>

#define BB 2
#define SS 4096
#define HH 1024
#define NHh 16
#define HD 64
#define LL 64
#define BS 64
#define RR 3
#define PENf (-10000.0f)

typedef unsigned int uint;
typedef __attribute__((ext_vector_type(8))) short bf16x8;
typedef __attribute__((ext_vector_type(4))) float f32x4;

__device__ __forceinline__ ushort f2bf(float f) {
    union { float f; uint u; } v; v.f = f;
    uint u = v.u;
    return (ushort)((u + 0x7fffu + ((u >> 16) & 1u)) >> 16);  // RNE
}
// packed f32x2 -> bf16x2 via HW cvt (RNE), 1 instr instead of ~10 VALU ops
__device__ __forceinline__ uint pack_bf(float a, float b) {
    uint r;
    asm("v_cvt_pk_bf16_f32 %0, %1, %2" : "=v"(r) : "v"(a), "v"(b));
    return r;
}
// scale both bf16 halves of a packed uint by 0.125 (exact, pow2)
__device__ __forceinline__ uint scale_pair(uint w) {
    float lo = __uint_as_float(w << 16) * 0.125f;
    float hi = __uint_as_float(w & 0xffff0000u) * 0.125f;
    return pack_bf(lo, hi);
}
__device__ __forceinline__ uint4 scale4(uint4 w) {
    uint4 o;
    o.x = scale_pair(w.x); o.y = scale_pair(w.y);
    o.z = scale_pair(w.z); o.w = scale_pair(w.w);
    return o;
}
// async global->LDS, 16B per lane; lds base must be wave-uniform (lane*16 auto)
__device__ __forceinline__ void async16(const ushort* g, ushort* l) {
    __builtin_amdgcn_global_load_lds((const __attribute__((address_space(1))) uint*)g,
                                     (__attribute__((address_space(3))) uint*)l,
                                     16, 0, 0);
}

// ---------------- fp32 -> bf16 convert (X and W), exact grid ----------------
// grid = 13824 blocks x 256: 12288 X-blocks then 1536 W-blocks (uniform branch).
__global__ __launch_bounds__(256)
void cvt_kernel(const float* __restrict__ Xq, const float* __restrict__ Xk,
                const float* __restrict__ Xv, const float* __restrict__ Wq,
                const float* __restrict__ Wk, const float* __restrict__ Wv,
                ushort* __restrict__ Xbf, ushort* __restrict__ Wbf)
{
    const size_t XTOT = (size_t)3 * BB * SS * HH;   // 25165824 = 3 * 2^23
    const uint u = blockIdx.x * 256 + threadIdx.x;
    const size_t e = (size_t)u * 8;
    const float* src; ushort* dst;
    if (e < XTOT) {
        const int zz = (int)(e >> 23);
        src = (zz == 0 ? Xq : zz == 1 ? Xk : Xv) + (e & ((1u << 23) - 1));
        dst = Xbf + e;
    } else {
        const size_t e2 = e - XTOT;
        const int zz = (int)(e2 >> 20);
        src = (zz == 0 ? Wq : zz == 1 ? Wk : Wv) + (e2 & ((1u << 20) - 1));
        dst = Wbf + e2;
    }
    float4 a = ((const float4*)src)[0];
    float4 c = ((const float4*)src)[1];
    uint4 o;
    o.x = pack_bf(a.x, a.y); o.y = pack_bf(a.z, a.w);
    o.z = pack_bf(c.x, c.y); o.w = pack_bf(c.z, c.w);
    *(uint4*)dst = o;
}

// ---------------- 256x256 bf16 GEMM, counted-vmcnt deep pipeline ----------------
// C[m][n] = sum_k A[m][k]*Bt[n][k] + bias[n]; A bf16 [8192][1024], Bt bf16 [1024][1024].
// BK=32, 4 LDS K-tile buffers, depth-3 prefetch, vmcnt(8) steady state (never 0),
// raw s_barrier per tile, setprio around MFMA cluster, XOR slot swizzle (2-way/free).
// launch_bounds(512) ONLY: min-waves=1 -> reg cap 512 total. R2's (512,2) capped
// total regs at 256 (128 arch + 128 acc) and spilled acc -> 700 MB scratch traffic.
// z=0 -> qb [bh][s][hd], z=1 -> kb, z=2 -> vbT [bh][hd][s].
__global__ __launch_bounds__(512)
void gemm8_kernel(const ushort* __restrict__ Xbf, const ushort* __restrict__ Wbf,
                  const float* __restrict__ bq, const float* __restrict__ bk,
                  const float* __restrict__ bv,
                  ushort* __restrict__ qb, ushort* __restrict__ kb,
                  ushort* __restrict__ vbT)
{
    // 4 x (A 256x32 + B 256x32) bf16 = 128 KiB
    __shared__ __align__(16) ushort smem8[65536];
    ushort* As_ = smem8;            // [4][256*32], swizzled slots
    ushort* Bs_ = smem8 + 32768;

    const int z = blockIdx.z;
    const ushort* Ag = Xbf + (size_t)z * ((size_t)BB * SS * HH);
    const ushort* Bg = Wbf + (size_t)z * (HH * HH);
    const float* bias = (z == 0) ? bq : (z == 1) ? bk : bv;
    const bool zv = (z == 2);

    const int tid = threadIdx.x;
    const int m0 = blockIdx.x * 256;
    const int n0 = blockIdx.y * 256;
    const int wave = tid >> 6;
    const int lane = tid & 63;
    const int l15 = lane & 15;
    const int quad = lane >> 4;
    const int wr = wave >> 2;      // 0..1 : m-half (128 rows)
    const int wc = wave & 3;       // 0..3 : n-quarter (64 rows)

    f32x4 acc[8][4];
#pragma unroll
    for (int mi = 0; mi < 8; ++mi)
#pragma unroll
        for (int ni = 0; ni < 4; ++ni) acc[mi][ni] = (f32x4){0.f, 0.f, 0.f, 0.f};

    // staging: thread t -> row t>>2 (+128 for 2nd load), phys slot t&3 holds
    // logical k-slot (t&3)^((row>>1)&3); same involution on the read side.
    const int trow = tid >> 2;
    const int tcol = ((tid & 3) ^ ((tid >> 3) & 3)) * 8;
    const ushort* Ath = Ag + (size_t)(m0 + trow) * HH + tcol;
    const ushort* Bth = Bg + (size_t)(n0 + trow) * HH + tcol;
    // read-side swizzled slot (row>>1)&3 == (l15>>1)&3 for all frag rows
    const int sl8 = (quad ^ ((l15 >> 1) & 3)) * 8;

#define STAGE8(kt_)                                                   \
    do {                                                              \
        const int k0_ = (kt_) * 32;                                   \
        const int sb_ = ((kt_) & 3) * 8192 + wave * 512;              \
        async16(Ath + k0_,            As_ + sb_);                     \
        async16(Ath + 128 * HH + k0_, As_ + sb_ + 4096);              \
        async16(Bth + k0_,            Bs_ + sb_);                     \
        async16(Bth + 128 * HH + k0_, Bs_ + sb_ + 4096);              \
    } while (0)

#define TILE_BODY(kt_, VM_, DOSTAGE_)                                              \
    do {                                                                           \
        const int bp_ = (kt_) & 3;                                                 \
        asm volatile("s_waitcnt vmcnt(" #VM_ ")" ::: "memory");                    \
        __builtin_amdgcn_s_barrier();                                              \
        __builtin_amdgcn_sched_barrier(0);                                         \
        const ushort* Ab_ = As_ + bp_ * 8192;                                      \
        const ushort* Bb_ = Bs_ + bp_ * 8192;                                      \
        bf16x8 af_[8], bf_[4];                                                     \
        _Pragma("unroll")                                                          \
        for (int ni = 0; ni < 4; ++ni)                                             \
            bf_[ni] = *(const bf16x8*)(Bb_ + (wc * 64 + ni * 16 + l15) * 32 + sl8);\
        _Pragma("unroll")                                                          \
        for (int mi = 0; mi < 8; ++mi)                                             \
            af_[mi] = *(const bf16x8*)(Ab_ + (wr * 128 + mi * 16 + l15) * 32 + sl8);\
        if (DOSTAGE_) STAGE8((kt_) + 3);                                           \
        __builtin_amdgcn_s_setprio(1);                                             \
        if (zv) {                                                                  \
            _Pragma("unroll")                                                      \
            for (int mi = 0; mi < 8; ++mi)                                         \
                _Pragma("unroll")                                                  \
                for (int ni = 0; ni < 4; ++ni)                                     \
                    acc[mi][ni] = __builtin_amdgcn_mfma_f32_16x16x32_bf16(         \
                        af_[mi], bf_[ni], acc[mi][ni], 0, 0, 0);                   \
        } else {                                                                   \
            _Pragma("unroll")                                                      \
            for (int mi = 0; mi < 8; ++mi)                                         \
                _Pragma("unroll")                                                  \
                for (int ni = 0; ni < 4; ++ni)                                     \
                    acc[mi][ni] = __builtin_amdgcn_mfma_f32_16x16x32_bf16(         \
                        bf_[ni], af_[mi], acc[mi][ni], 0, 0, 0);                   \
        }                                                                          \
        __builtin_amdgcn_s_setprio(0);                                             \
    } while (0)

    STAGE8(0); STAGE8(1); STAGE8(2);          // 12 loads in flight

    for (int k4 = 0; k4 < 28; k4 += 4) {      // kt = 0..27, all stage kt+3
        TILE_BODY(k4 + 0, 8, 1);
        TILE_BODY(k4 + 1, 8, 1);
        TILE_BODY(k4 + 2, 8, 1);
        TILE_BODY(k4 + 3, 8, 1);
    }
    TILE_BODY(28, 8, 1);                      // stages tile 31
    TILE_BODY(29, 8, 0);
    TILE_BODY(30, 4, 0);
    TILE_BODY(31, 0, 0);
#undef TILE_BODY
#undef STAGE8

    if (!zv) {
        // acc[mi][ni]: D row = n-local (wc*64+ni*16+quad*4+rr), col = m-local (wr*128+mi*16+l15)
        ushort* outp = (z == 0) ? qb : kb;
#pragma unroll
        for (int ni = 0; ni < 4; ++ni) {
            const int nb = n0 + wc * 64 + ni * 16 + quad * 4;   // 4 consecutive n (hd)
            const float4 b4 = *(const float4*)&bias[nb];
            const int nh = nb >> 6;
            const int hd = nb & 63;
#pragma unroll
            for (int mi = 0; mi < 8; ++mi) {
                const int m = m0 + wr * 128 + mi * 16 + l15;
                const int bgl = m >> 12, s = m & 4095;
                uint2 pk;
                pk.x = pack_bf(acc[mi][ni][0] + b4.x, acc[mi][ni][1] + b4.y);
                pk.y = pack_bf(acc[mi][ni][2] + b4.z, acc[mi][ni][3] + b4.w);
                *(uint2*)&outp[((size_t)((bgl << 4) | nh) * SS + s) * HD + hd] = pk;
            }
        }
    } else {
        // V: acc[mi][ni]: D row = m-local (quad*4+rr), col = n-local (l15).
        // restage transposed in LDS (two 128-n passes), coalesced store to vbT [bh][hd][s]
        __syncthreads();
        ushort* stg = smem8;   // [128 n][272 m]
        const int bgl = m0 >> 12;
#pragma unroll
        for (int p = 0; p < 2; ++p) {
            __syncthreads();
            if ((wc >> 1) == p) {
#pragma unroll
                for (int ni = 0; ni < 4; ++ni) {
                    const int nl = (wc & 1) * 64 + ni * 16 + l15;
                    const float bn = bias[n0 + p * 128 + nl];
#pragma unroll
                    for (int mi = 0; mi < 8; ++mi) {
                        const int mb = wr * 128 + mi * 16 + quad * 4;
                        uint2 pk;
                        pk.x = pack_bf(acc[mi][ni][0] + bn, acc[mi][ni][1] + bn);
                        pk.y = pack_bf(acc[mi][ni][2] + bn, acc[mi][ni][3] + bn);
                        *(uint2*)(stg + nl * 272 + mb) = pk;
                    }
                }
            }
            __syncthreads();
            {
                const int row = tid >> 2;      // 0..127
                const int seg = tid & 3;       // 64-m segment
                const int n = n0 + p * 128 + row;
                const int nh = n >> 6, hd = n & 63;
                const uint4* src = (const uint4*)(stg + row * 272 + seg * 64);
                uint4* dst = (uint4*)(vbT + ((size_t)((bgl << 4) | nh) * HD + hd) * SS
                                      + (m0 & 4095) + seg * 64);
#pragma unroll
                for (int jj = 0; jj < 8; ++jj) dst[jj] = src[jj];
            }
        }
    }
}

// ---------------- R1 fallback projection (inline convert) ----------------
__global__ __launch_bounds__(256)
void proj3_kernel(const float* __restrict__ Xq, const float* __restrict__ Xk,
                  const float* __restrict__ Xv,
                  const float* __restrict__ Wq, const float* __restrict__ Wk,
                  const float* __restrict__ Wv,
                  const float* __restrict__ bq, const float* __restrict__ bk,
                  const float* __restrict__ bv,
                  ushort* __restrict__ qb, ushort* __restrict__ kb,
                  ushort* __restrict__ vbT)
{
    __shared__ __align__(16) ushort smem[128 * 136];
    ushort* As = smem;             // [128][40]
    ushort* Bs = smem + 128 * 40;  // [128][40]

    const int z = blockIdx.z;
    const float* X    = (z == 0) ? Xq : (z == 1) ? Xk : Xv;
    const float* W    = (z == 0) ? Wq : (z == 1) ? Wk : Wv;
    const float* bias = (z == 0) ? bq : (z == 1) ? bk : bv;

    const int tid = threadIdx.x;
    const int m0 = blockIdx.x * 128;
    const int n0 = blockIdx.y * 128;
    const int wave = tid >> 6;
    const int lane = tid & 63;
    const int l15 = lane & 15;
    const int quad = lane >> 4;
    const int wr = wave >> 1, wc = wave & 1;

    f32x4 acc[4][4];
#pragma unroll
    for (int mt = 0; mt < 4; ++mt)
#pragma unroll
        for (int nt = 0; nt < 4; ++nt) acc[mt][nt] = (f32x4){0.f, 0.f, 0.f, 0.f};

    const int srow = tid >> 1;
    const int shalf = tid & 1;
    const float* xp = X + (size_t)(m0 + srow) * HH + shalf * 16;
    const float* wp = W + (size_t)(n0 + srow) * HH + shalf * 16;
    ushort* asw = As + srow * 40 + shalf * 16;
    ushort* bsw = Bs + srow * 40 + shalf * 16;

    for (int k0 = 0; k0 < HH; k0 += 32) {
        float4 a0 = *(const float4*)(xp + k0);
        float4 a1 = *(const float4*)(xp + k0 + 4);
        float4 a2 = *(const float4*)(xp + k0 + 8);
        float4 a3 = *(const float4*)(xp + k0 + 12);
        float4 b0 = *(const float4*)(wp + k0);
        float4 b1 = *(const float4*)(wp + k0 + 4);
        float4 b2 = *(const float4*)(wp + k0 + 8);
        float4 b3 = *(const float4*)(wp + k0 + 12);
        __syncthreads();
        uint4 pa, pb;
        pa.x = pack_bf(a0.x, a0.y); pa.y = pack_bf(a0.z, a0.w);
        pa.z = pack_bf(a1.x, a1.y); pa.w = pack_bf(a1.z, a1.w);
        *(uint4*)asw = pa;
        pa.x = pack_bf(a2.x, a2.y); pa.y = pack_bf(a2.z, a2.w);
        pa.z = pack_bf(a3.x, a3.y); pa.w = pack_bf(a3.z, a3.w);
        *(uint4*)(asw + 8) = pa;
        pb.x = pack_bf(b0.x, b0.y); pb.y = pack_bf(b0.z, b0.w);
        pb.z = pack_bf(b1.x, b1.y); pb.w = pack_bf(b1.z, b1.w);
        *(uint4*)bsw = pb;
        pb.x = pack_bf(b2.x, b2.y); pb.y = pack_bf(b2.z, b2.w);
        pb.z = pack_bf(b3.x, b3.y); pb.w = pack_bf(b3.z, b3.w);
        *(uint4*)(bsw + 8) = pb;
        __syncthreads();

        bf16x8 af[4], bfr[4];
#pragma unroll
        for (int mt = 0; mt < 4; ++mt)
            af[mt] = *(const bf16x8*)(As + (wr * 64 + mt * 16 + l15) * 40 + quad * 8);
#pragma unroll
        for (int nt = 0; nt < 4; ++nt)
            bfr[nt] = *(const bf16x8*)(Bs + (wc * 64 + nt * 16 + l15) * 40 + quad * 8);
#pragma unroll
        for (int mt = 0; mt < 4; ++mt)
#pragma unroll
            for (int nt = 0; nt < 4; ++nt)
                acc[mt][nt] = __builtin_amdgcn_mfma_f32_16x16x32_bf16(af[mt], bfr[nt], acc[mt][nt], 0, 0, 0);
    }

    if (z < 2) {
        ushort* outp = (z == 0) ? qb : kb;
#pragma unroll
        for (int nt = 0; nt < 4; ++nt) {
            const int n = n0 + wc * 64 + nt * 16 + l15;
            const float bn = bias[n];
            const int nh = n >> 6, hd = n & 63;
#pragma unroll
            for (int mt = 0; mt < 4; ++mt) {
#pragma unroll
                for (int rr = 0; rr < 4; ++rr) {
                    const int m = m0 + wr * 64 + mt * 16 + quad * 4 + rr;
                    const int bgl = m >> 12, s = m & 4095;
                    outp[((size_t)((bgl << 4) | nh) * SS + s) * HD + hd] = f2bf(acc[mt][nt][rr] + bn);
                }
            }
        }
    } else {
        __syncthreads();
        ushort* stg = smem;
#pragma unroll
        for (int nt = 0; nt < 4; ++nt) {
            const int n_local = wc * 64 + nt * 16 + l15;
            const float bn = bias[n0 + n_local];
#pragma unroll
            for (int mt = 0; mt < 4; ++mt) {
                const int m_base = wr * 64 + mt * 16 + quad * 4;
                uint2 pk;
                pk.x = pack_bf(acc[mt][nt][0] + bn, acc[mt][nt][1] + bn);
                pk.y = pack_bf(acc[mt][nt][2] + bn, acc[mt][nt][3] + bn);
                *(uint2*)(stg + n_local * 136 + m_base) = pk;
            }
        }
        __syncthreads();
        const int n_row = tid >> 1;
        const int half = tid & 1;
        const int n = n0 + n_row;
        const int nh = n >> 6, hd = n & 63;
        const int bgl = m0 >> 12;
        const int sbase = (m0 & 4095) + half * 64;
        const uint4* src = (const uint4*)(stg + n_row * 136 + half * 64);
        uint4* dst = (uint4*)(vbT + ((size_t)((bgl << 4) | nh) * HD + hd) * SS + sbase);
#pragma unroll
        for (int j = 0; j < 8; ++j) dst[j] = src[j];
    }
}

// ---------------- block-sparse attention, S^T + dbuf single-barrier ----------------
// qg/kg bf16 [bh][s][d]; vTg bf16 [bh][d][s]; out f32 [b][s][h*d].
// K/V LDS tiles use an XOR column swizzle (slot ^= (row>>1)&3) applied BOTH at the
// global source of global_load_lds (linear LDS dest) and at the ds_read side.
__global__ __launch_bounds__(256)
void attn_kernel(const ushort* __restrict__ qg, const ushort* __restrict__ kg,
                 const ushort* __restrict__ vTg,
                 const float* __restrict__ mask, const int* __restrict__ rand_attn,
                 float* __restrict__ out, float* __restrict__ partO,
                 float* __restrict__ partML)
{
    __shared__ __align__(16) ushort qs_ps[64][72];      // q staging, then ps (wave-private bands)
    __shared__ __align__(16) ushort ks2[2][2][64][32];  // [buf][k-chunk][kc][d32] (col-swizzled)
    __shared__ __align__(16) ushort vs2[2][2][64][32];  // [buf][kc-chunk][d][kc32] (col-swizzled)
    __shared__ __align__(16) float qm_s[64];
    __shared__ __align__(16) float km_s[2][64];

    const int tid = threadIdx.x;
    const int wid = blockIdx.x;
    const int bh = wid / 78;
    const int r = wid - bh * 78;
    const int b = bh >> 4, h = bh & 15;

    int i, nkb;
    int kbl[8], pfl[8];
    bool dense;
    int part = 0, which = 0;
    if (r < 62) {
        dense = false;
        i = r + 1;
        const int* ra = rand_attn + ((size_t)h * (LL - 2) + (i - 1)) * RR;
        if (i == 1) {
            kbl[0] = 0; kbl[1] = 1; kbl[2] = 2; kbl[3] = LL - 1;
            kbl[4] = ra[0]; kbl[5] = ra[1]; kbl[6] = ra[2]; kbl[7] = 0;
            pfl[0] = pfl[1] = pfl[2] = pfl[3] = 0;
            pfl[4] = pfl[5] = pfl[6] = 1; pfl[7] = 0;
            nkb = 7;
        } else if (i == LL - 2) {
            kbl[0] = 0; kbl[1] = LL - 3; kbl[2] = LL - 2; kbl[3] = LL - 1;
            kbl[4] = ra[0]; kbl[5] = ra[1]; kbl[6] = ra[2]; kbl[7] = 0;
            pfl[0] = pfl[1] = pfl[2] = pfl[3] = 0;
            pfl[4] = pfl[5] = pfl[6] = 1; pfl[7] = 0;
            nkb = 7;
        } else {
            kbl[0] = 0;      pfl[0] = 0;
            kbl[1] = i - 1;  pfl[1] = 1;
            kbl[2] = i;      pfl[2] = 1;
            kbl[3] = i + 1;  pfl[3] = 1;
            kbl[4] = LL - 1; pfl[4] = 0;
            kbl[5] = ra[0]; kbl[6] = ra[1]; kbl[7] = ra[2];
            pfl[5] = pfl[6] = pfl[7] = 1;
            nkb = 8;
        }
    } else {
        dense = true;
        const int r2 = r - 62;
        which = r2 >> 3;
        part = r2 & 7;
        i = which ? (LL - 1) : 0;
        nkb = 8;
#pragma unroll
        for (int j = 0; j < 8; ++j) { kbl[j] = part * 8 + j; pfl[j] = 0; }
    }

    const int lane = tid & 63;
    const int wave = tid >> 6;
    const int l15 = lane & 15;
    const int quad = lane >> 4;
    const int srow = lane >> 2;
    // swizzled 16B-slot for K/V staging: slot ^= (row_in_16 >> 1) & 3
    const int p8s = (((lane & 3) ^ ((srow >> 1) & 3))) * 8;
    const ushort* kgb = kg + (size_t)bh * SS * HD;
    const ushort* vgb = vTg + (size_t)bh * HD * SS;

#define STAGE_KV(kb_, bp)                                                        \
    do {                                                                         \
        const size_t krow = (size_t)((kb_) * BS + wave * 16 + srow) * HD;        \
        async16(kgb + krow + p8s,      &ks2[bp][0][wave * 16][0]);               \
        async16(kgb + krow + 32 + p8s, &ks2[bp][1][wave * 16][0]);               \
        const size_t vrow = (size_t)(wave * 16 + srow) * SS + (kb_) * BS;        \
        async16(vgb + vrow + p8s,      &vs2[bp][0][wave * 16][0]);               \
        async16(vgb + vrow + 32 + p8s, &vs2[bp][1][wave * 16][0]);               \
    } while (0)

    // stage q (scaled by rsd) + masks + first K/V buffer
    {
        const int row = tid >> 2;
        const int c0 = (tid & 3) * 16;
        const ushort* src = qg + ((size_t)bh * SS + i * BS + row) * HD + c0;
        uint4 w0 = *(const uint4*)src;
        uint4 w1 = *(const uint4*)(src + 8);
        *(uint4*)&qs_ps[row][c0] = scale4(w0);
        *(uint4*)&qs_ps[row][c0 + 8] = scale4(w1);
        if (tid < 64) qm_s[tid] = mask[(size_t)b * SS + i * BS + tid];
    }
    STAGE_KV(kbl[0], 0);
    if (tid < 64) km_s[0][tid] = mask[(size_t)b * SS + kbl[0] * BS + tid];
    __syncthreads();  // publish qs, buf0, masks

    // hoist q fragments (B-operand, n=q=wave*16+l15); qs region becomes ps after this
    bf16x8 aq[2];
    aq[0] = *(const bf16x8*)&qs_ps[wave * 16 + l15][quad * 8];
    aq[1] = *(const bf16x8*)&qs_ps[wave * 16 + l15][32 + quad * 8];
    const float qm = qm_s[wave * 16 + l15];

    // swizzled read slot for K/V tiles (same involution as p8s, row_in_16 = l15)
    const int sqz = (quad ^ ((l15 >> 1) & 3)) * 8;

    float mrow = -1e30f, lrow = 0.0f;   // per-lane, q = wave*16 + l15
    f32x4 accO[4];
#pragma unroll
    for (int dt = 0; dt < 4; ++dt) accO[dt] = (f32x4){0.f, 0.f, 0.f, 0.f};

    for (int it = 0; it < nkb; ++it) {
        const int cur = it & 1;
        if (it + 1 < nkb) {
            STAGE_KV(kbl[it + 1], cur ^ 1);   // flies during this iter's compute
            if (tid < 64) km_s[cur ^ 1][tid] = mask[(size_t)b * SS + kbl[it + 1] * BS + tid];
        }
        const int pf = pfl[it];

        // S^T = K . Q^T : A = K rows (m=kc), B = Q rows (n=q)
        f32x4 sc[4];
#pragma unroll
        for (int nt = 0; nt < 4; ++nt) sc[nt] = (f32x4){0.f, 0.f, 0.f, 0.f};
#pragma unroll
        for (int c = 0; c < 2; ++c) {
#pragma unroll
            for (int nt = 0; nt < 4; ++nt) {
                bf16x8 af = *(const bf16x8*)&ks2[cur][c][nt * 16 + l15][sqz];
                sc[nt] = __builtin_amdgcn_mfma_f32_16x16x32_bf16(af, aq[c], sc[nt], 0, 0, 0);
            }
        }

        // penalties: lane holds (q = wave*16+l15, kc = nt*16+quad*4+rr)
        float p[4][4];
        float bm = -1e30f;
#pragma unroll
        for (int nt = 0; nt < 4; ++nt) {
            const float4 km4 = *(const float4*)&km_s[cur][nt * 16 + quad * 4];
            const float kmv[4] = {km4.x, km4.y, km4.z, km4.w};
#pragma unroll
            for (int rr = 0; rr < 4; ++rr) {
                const float pm = pf ? (qm * kmv[rr]) : kmv[rr];
                const float sv = sc[nt][rr] + (1.0f - pm) * PENf;
                p[nt][rr] = sv;
                bm = fmaxf(bm, sv);
            }
        }
        bm = fmaxf(bm, __shfl_xor(bm, 16));
        bm = fmaxf(bm, __shfl_xor(bm, 32));
        // defer-max (T13): only rescale when some row's max grew by > 8
        if (!__all(bm - mrow <= 8.0f)) {
            const float mn = fmaxf(mrow, bm);
            const float alpha = __expf(mrow - mn);
            mrow = mn;
            float a4[4];
#pragma unroll
            for (int rr = 0; rr < 4; ++rr) a4[rr] = __shfl(alpha, quad * 4 + rr, 64);
#pragma unroll
            for (int dt = 0; dt < 4; ++dt) {
#pragma unroll
                for (int rr = 0; rr < 4; ++rr) accO[dt][rr] *= a4[rr];
            }
            lrow *= alpha;
        }
        float ls = 0.0f;
#pragma unroll
        for (int nt = 0; nt < 4; ++nt)
#pragma unroll
            for (int rr = 0; rr < 4; ++rr) {
                p[nt][rr] = __expf(p[nt][rr] - mrow);   // bounded by e^8 when deferred
                ls += p[nt][rr];
            }
        ls += __shfl_xor(ls, 16);
        ls += __shfl_xor(ls, 32);
        lrow += ls;

        // write P (bf16) into wave-private ps rows; b64 stores
#pragma unroll
        for (int nt = 0; nt < 4; ++nt) {
            uint2 pk;
            pk.x = pack_bf(p[nt][0], p[nt][1]);
            pk.y = pack_bf(p[nt][2], p[nt][3]);
            *(uint2*)&qs_ps[wave * 16 + l15][nt * 16 + quad * 4] = pk;
        }

        // PV: A = ps (m=q), B = vs2 (n=d); ps is wave-private -> no barrier
#pragma unroll
        for (int c = 0; c < 2; ++c) {
            bf16x8 ap = *(const bf16x8*)&qs_ps[wave * 16 + l15][c * 32 + quad * 8];
#pragma unroll
            for (int dt = 0; dt < 4; ++dt) {
                bf16x8 bvf = *(const bf16x8*)&vs2[cur][c][dt * 16 + l15][sqz];
                accO[dt] = __builtin_amdgcn_mfma_f32_16x16x32_bf16(ap, bvf, accO[dt], 0, 0, 0);
            }
        }

        if (it + 1 < nkb) __syncthreads();  // publish buf cur^1; protect buf reuse
    }
#undef STAGE_KV

    if (!dense) {
#pragma unroll
        for (int rr = 0; rr < 4; ++rr) {
            const int qloc = quad * 4 + rr;
            const float lq = __shfl(lrow, qloc, 64);
            const float inv = qm_s[wave * 16 + qloc] / lq;
#pragma unroll
            for (int dt = 0; dt < 4; ++dt) {
                const int d = dt * 16 + l15;
                out[((size_t)b * SS + i * BS + wave * 16 + qloc) * HH + h * HD + d] = accO[dt][rr] * inv;
            }
        }
    } else {
        const int slot = (bh * 2 + which) * 8 + part;
        float* po = partO + (size_t)slot * 4096;
#pragma unroll
        for (int rr = 0; rr < 4; ++rr) {
            const int qrow = wave * 16 + quad * 4 + rr;
#pragma unroll
            for (int dt = 0; dt < 4; ++dt) {
                const int d = dt * 16 + l15;
                po[qrow * 64 + d] = accO[dt][rr];
            }
        }
        if (lane < 16) {
            partML[slot * 128 + wave * 16 + lane] = mrow;
            partML[slot * 128 + 64 + wave * 16 + lane] = lrow;
        }
    }
}

// ---------------- combine partials for dense query blocks ----------------
// 256 blocks x 64 threads -> engage all CUs; latency-bound.
__global__ __launch_bounds__(64)
void combine_kernel(const float* __restrict__ partO, const float* __restrict__ partML,
                    const float* __restrict__ mask, float* __restrict__ out)
{
    const int g4 = blockIdx.x;    // (bh*2 + which) * 4 + row-quarter
    const int g = g4 >> 2;
    const int bh = g >> 1, which = g & 1;
    const int b = bh >> 4, h = bh & 15;
    const int i = which ? (LL - 1) : 0;
    const int t = threadIdx.x;
    const int row = ((g4 & 3) << 4) | (t >> 2);
    const int d0 = (t & 3) * 16;
    const int base = g * 8;

    float mp[8], lp[8];
    float M = -1e30f;
#pragma unroll
    for (int p = 0; p < 8; ++p) {
        mp[p] = partML[(base + p) * 128 + row];
        lp[p] = partML[(base + p) * 128 + 64 + row];
        M = fmaxf(M, mp[p]);
    }
    float L = 0.0f, w[8];
#pragma unroll
    for (int p = 0; p < 8; ++p) { w[p] = __expf(mp[p] - M); L += lp[p] * w[p]; }

    float4 o[4];
#pragma unroll
    for (int j = 0; j < 4; ++j) o[j] = make_float4(0.f, 0.f, 0.f, 0.f);
#pragma unroll
    for (int p = 0; p < 8; ++p) {
        const float* po = partO + (size_t)(base + p) * 4096 + row * 64 + d0;
#pragma unroll
        for (int j = 0; j < 4; ++j) {
            float4 v = *(const float4*)(po + j * 4);
            o[j].x = fmaf(w[p], v.x, o[j].x);
            o[j].y = fmaf(w[p], v.y, o[j].y);
            o[j].z = fmaf(w[p], v.z, o[j].z);
            o[j].w = fmaf(w[p], v.w, o[j].w);
        }
    }
    const float fm = mask[(size_t)b * SS + i * BS + row];
    const float inv = fm / L;
    float* dst = out + ((size_t)b * SS + i * BS + row) * HH + h * HD + d0;
#pragma unroll
    for (int j = 0; j < 4; ++j) {
        float4 v;
        v.x = o[j].x * inv; v.y = o[j].y * inv;
        v.z = o[j].z * inv; v.w = o[j].w * inv;
        *(float4*)(dst + j * 4) = v;
    }
}

extern "C" void kernel_launch(void* const* d_in, const int* in_sizes, int n_in,
                              void* d_out, int out_size, void* d_ws, size_t ws_size,
                              hipStream_t stream) {
    (void)in_sizes; (void)n_in; (void)out_size;
    const float* Q    = (const float*)d_in[0];
    const float* K    = (const float*)d_in[1];
    const float* V    = (const float*)d_in[2];
    const float* mask = (const float*)d_in[3];
    const float* Wq   = (const float*)d_in[4];
    const float* bq   = (const float*)d_in[5];
    const float* Wk   = (const float*)d_in[6];
    const float* bk   = (const float*)d_in[7];
    const float* Wv   = (const float*)d_in[8];
    const float* bv   = (const float*)d_in[9];
    const int*   ra   = (const int*)d_in[10];
    float* out = (float*)d_out;

    const size_t qkv = (size_t)BB * NHh * SS * HD;  // 8388608 elems
    ushort* qb  = (ushort*)d_ws;
    ushort* kb  = qb + qkv;
    ushort* vbT = kb + qkv;
    float* partO  = (float*)(vbT + qkv);            // 512 * 4096 f32
    float* partML = partO + (size_t)512 * 4096;     // 512 * 128 f32
    ushort* Xbf = (ushort*)(partML + (size_t)512 * 128);
    ushort* Wbf = Xbf + 3 * qkv;
    const size_t need = (size_t)((char*)(Wbf + (size_t)3 * HH * HH) - (char*)d_ws);

    if (ws_size >= need) {
        cvt_kernel<<<13824, 256, 0, stream>>>(Q, K, V, Wq, Wk, Wv, Xbf, Wbf);
        gemm8_kernel<<<dim3(32, 4, 3), 512, 0, stream>>>(Xbf, Wbf, bq, bk, bv, qb, kb, vbT);
    } else {
        proj3_kernel<<<dim3(64, 8, 3), 256, 0, stream>>>(Q, K, V, Wq, Wk, Wv, bq, bk, bv,
                                                         qb, kb, vbT);
    }
    attn_kernel<<<dim3(BB * NHh * 78), 256, 0, stream>>>(qb, kb, vbT, mask, ra,
                                                         out, partO, partML);
    combine_kernel<<<dim3(BB * NHh * 2 * 4), 64, 0, stream>>>(partO, partML, mask, out);
}

// Round 4
// 280.916 us; speedup vs baseline: 1.9924x; 1.9908x over previous
//
#include <hip/hip_runtime.h>
#include <hip/hip_bf16.h>
#include <stdint.h>

#define BB 2
#define SS 4096
#define HH 1024
#define NHh 16
#define HD 64
#define LL 64
#define BS 64
#define RR 3
#define PENf (-10000.0f)

typedef unsigned int uint;
typedef __attribute__((ext_vector_type(8))) short bf16x8;
typedef __attribute__((ext_vector_type(4))) float f32x4;

__device__ __forceinline__ ushort f2bf(float f) {
    union { float f; uint u; } v; v.f = f;
    uint u = v.u;
    return (ushort)((u + 0x7fffu + ((u >> 16) & 1u)) >> 16);  // RNE
}
// packed f32x2 -> bf16x2 via HW cvt (RNE)
__device__ __forceinline__ uint pack_bf(float a, float b) {
    uint r;
    asm("v_cvt_pk_bf16_f32 %0, %1, %2" : "=v"(r) : "v"(a), "v"(b));
    return r;
}
// scale both bf16 halves of a packed uint by 0.125 (exact, pow2)
__device__ __forceinline__ uint scale_pair(uint w) {
    float lo = __uint_as_float(w << 16) * 0.125f;
    float hi = __uint_as_float(w & 0xffff0000u) * 0.125f;
    return pack_bf(lo, hi);
}
__device__ __forceinline__ uint4 scale4(uint4 w) {
    uint4 o;
    o.x = scale_pair(w.x); o.y = scale_pair(w.y);
    o.z = scale_pair(w.z); o.w = scale_pair(w.w);
    return o;
}
// async global->LDS, 16B per lane; lds base must be wave-uniform (lane*16 auto)
__device__ __forceinline__ void async16(const ushort* g, ushort* l) {
    __builtin_amdgcn_global_load_lds((const __attribute__((address_space(1))) uint*)g,
                                     (__attribute__((address_space(3))) uint*)l,
                                     16, 0, 0);
}

// ---------------- fp32 -> bf16 convert (X and W), exact grid ----------------
__global__ __launch_bounds__(256)
void cvt_kernel(const float* __restrict__ Xq, const float* __restrict__ Xk,
                const float* __restrict__ Xv, const float* __restrict__ Wq,
                const float* __restrict__ Wk, const float* __restrict__ Wv,
                ushort* __restrict__ Xbf, ushort* __restrict__ Wbf)
{
    const size_t XTOT = (size_t)3 * BB * SS * HH;   // 25165824 = 3 * 2^23
    const uint u = blockIdx.x * 256 + threadIdx.x;
    const size_t e = (size_t)u * 8;
    const float* src; ushort* dst;
    if (e < XTOT) {
        const int zz = (int)(e >> 23);
        src = (zz == 0 ? Xq : zz == 1 ? Xk : Xv) + (e & ((1u << 23) - 1));
        dst = Xbf + e;
    } else {
        const size_t e2 = e - XTOT;
        const int zz = (int)(e2 >> 20);
        src = (zz == 0 ? Wq : zz == 1 ? Wk : Wv) + (e2 & ((1u << 20) - 1));
        dst = Wbf + e2;
    }
    float4 a = ((const float4*)src)[0];
    float4 c = ((const float4*)src)[1];
    uint4 o;
    o.x = pack_bf(a.x, a.y); o.y = pack_bf(a.z, a.w);
    o.z = pack_bf(c.x, c.y); o.w = pack_bf(c.z, c.w);
    *(uint4*)dst = o;
}

// ---------------- 128x256 bf16 GEMM, counted-vmcnt pipeline, acc 4x4 ----------------
// C[m][n] = sum_k A[m][k]*Bt[n][k] + bias[n]; A bf16 [8192][1024], Bt bf16 [1024][1024].
// 8 waves (2m x 4n), per-wave 64x64 -> acc 4x4 f32x4 = 64 regs (gemm3's spill-free
// footprint). BK=32, 4 LDS buffers (96 KiB), depth-3 prefetch, steady vmcnt(6),
// raw s_barrier, setprio, both-sides XOR slot swizzle.
// z=0 -> qb [bh][s][hd], z=1 -> kb, z=2 -> vbT [bh][hd][s].
__global__ __launch_bounds__(512)
void gemm6_kernel(const ushort* __restrict__ Xbf, const ushort* __restrict__ Wbf,
                  const float* __restrict__ bq, const float* __restrict__ bk,
                  const float* __restrict__ bv,
                  ushort* __restrict__ qb, ushort* __restrict__ kb,
                  ushort* __restrict__ vbT)
{
    // per buf (24KB): A [128][32] at +0 (4096 elems), B [256][32] at +4096 (8192 elems)
    __shared__ __align__(16) ushort smem6[49152];   // 96 KiB

    const int z = blockIdx.z;
    const ushort* Ag = Xbf + (size_t)z * ((size_t)BB * SS * HH);
    const ushort* Bg = Wbf + (size_t)z * (HH * HH);
    const float* bias = (z == 0) ? bq : (z == 1) ? bk : bv;
    const bool zv = (z == 2);

    const int tid = threadIdx.x;
    const int m0 = blockIdx.x * 128;
    const int n0 = blockIdx.y * 256;
    const int wave = tid >> 6;
    const int lane = tid & 63;
    const int l15 = lane & 15;
    const int quad = lane >> 4;
    const int wr = wave >> 2;      // 0..1 : m-half (64 rows each)
    const int wc = wave & 3;       // 0..3 : n-quarter (64 rows each)

    f32x4 acc[4][4];
#pragma unroll
    for (int i = 0; i < 4; ++i)
#pragma unroll
        for (int j = 0; j < 4; ++j) acc[i][j] = (f32x4){0.f, 0.f, 0.f, 0.f};

    // staging: thread t -> row t>>2, phys 16B-slot t&3 holds logical slot
    // (t&3)^((row>>1)&3); same involution on the read side.
    const int trow = tid >> 2;
    const int tcol = ((tid & 3) ^ ((tid >> 3) & 3)) * 8;
    const ushort* Ath  = Ag + (size_t)(m0 + trow) * HH + tcol;          // A rows 0..127
    const ushort* Bth  = Bg + (size_t)(n0 + trow) * HH + tcol;          // B rows 0..127
    const ushort* Bth2 = Bth + (size_t)128 * HH;                        // B rows 128..255
    // read-side swizzled slot ((row>>1)&3 == (l15>>1)&3 for all frag rows)
    const int sl8 = (quad ^ ((l15 >> 1) & 3)) * 8;

#define STAGE6(kt_)                                                    \
    do {                                                               \
        const int k0_ = (kt_) * 32;                                    \
        const int sb_ = ((kt_) & 3) * 12288 + wave * 512;              \
        async16(Ath + k0_,  smem6 + sb_);                              \
        async16(Bth + k0_,  smem6 + sb_ + 4096);                       \
        async16(Bth2 + k0_, smem6 + sb_ + 8192);                       \
    } while (0)

#define TB6(kt_, VM_, DOSTAGE_)                                                     \
    do {                                                                            \
        const int bo_ = ((kt_) & 3) * 12288;                                        \
        asm volatile("s_waitcnt vmcnt(" #VM_ ")" ::: "memory");                     \
        __builtin_amdgcn_s_barrier();                                               \
        __builtin_amdgcn_sched_barrier(0);                                          \
        const ushort* Ab_ = smem6 + bo_;                                            \
        const ushort* Bb_ = smem6 + bo_ + 4096;                                     \
        bf16x8 af_[4], bf_[4];                                                      \
        _Pragma("unroll")                                                           \
        for (int mt = 0; mt < 4; ++mt)                                              \
            af_[mt] = *(const bf16x8*)(Ab_ + (wr * 64 + mt * 16 + l15) * 32 + sl8); \
        _Pragma("unroll")                                                           \
        for (int nt = 0; nt < 4; ++nt)                                              \
            bf_[nt] = *(const bf16x8*)(Bb_ + (wc * 64 + nt * 16 + l15) * 32 + sl8); \
        if (DOSTAGE_) STAGE6((kt_) + 3);                                            \
        __builtin_amdgcn_s_setprio(1);                                              \
        if (zv) {                                                                   \
            _Pragma("unroll")                                                       \
            for (int i = 0; i < 4; ++i)                                             \
                _Pragma("unroll")                                                   \
                for (int j = 0; j < 4; ++j)                                         \
                    acc[i][j] = __builtin_amdgcn_mfma_f32_16x16x32_bf16(            \
                        af_[i], bf_[j], acc[i][j], 0, 0, 0);                        \
        } else {                                                                    \
            _Pragma("unroll")                                                       \
            for (int i = 0; i < 4; ++i)                                             \
                _Pragma("unroll")                                                   \
                for (int j = 0; j < 4; ++j)                                         \
                    acc[i][j] = __builtin_amdgcn_mfma_f32_16x16x32_bf16(            \
                        bf_[i], af_[j], acc[i][j], 0, 0, 0);                        \
        }                                                                           \
        __builtin_amdgcn_s_setprio(0);                                              \
    } while (0)

    STAGE6(0); STAGE6(1); STAGE6(2);          // 9 loads in flight

    for (int k4 = 0; k4 < 28; k4 += 4) {      // kt = 0..27 stage kt+3 (3..30)
        TB6(k4 + 0, 6, 1);
        TB6(k4 + 1, 6, 1);
        TB6(k4 + 2, 6, 1);
        TB6(k4 + 3, 6, 1);
    }
    TB6(28, 6, 1);                            // stages tile 31
    TB6(29, 6, 0);
    TB6(30, 3, 0);
    TB6(31, 0, 0);
#undef TB6
#undef STAGE6

    if (!zv) {
        // acc[wt][xt]: D row = n-local (wc*64+wt*16+quad*4+rr), col = m-local (wr*64+xt*16+l15)
        ushort* outp = (z == 0) ? qb : kb;
#pragma unroll
        for (int wt = 0; wt < 4; ++wt) {
            const int nb = n0 + wc * 64 + wt * 16 + quad * 4;   // 4 consecutive n (hd)
            const float4 b4 = *(const float4*)&bias[nb];
            const int nh = nb >> 6;
            const int hd = nb & 63;
#pragma unroll
            for (int xt = 0; xt < 4; ++xt) {
                const int m = m0 + wr * 64 + xt * 16 + l15;
                const int bgl = m >> 12, s = m & 4095;
                uint2 pk;
                pk.x = pack_bf(acc[wt][xt][0] + b4.x, acc[wt][xt][1] + b4.y);
                pk.y = pack_bf(acc[wt][xt][2] + b4.z, acc[wt][xt][3] + b4.w);
                *(uint2*)&outp[((size_t)((bgl << 4) | nh) * SS + s) * HD + hd] = pk;
            }
        }
    } else {
        // V: acc[mt][nt]: D row = m-local (wr*64+mt*16+quad*4+rr), col = n-local (wc*64+nt*16+l15)
        // restage transposed in LDS, then coalesced store to vbT [bh][hd][s]
        __syncthreads();
        ushort* stg = smem6;   // [256 n][136 m] = 68 KiB
        const int bgl = m0 >> 12;
#pragma unroll
        for (int nt = 0; nt < 4; ++nt) {
            const int n_local = wc * 64 + nt * 16 + l15;
            const float bn = bias[n0 + n_local];
#pragma unroll
            for (int mt = 0; mt < 4; ++mt) {
                const int m_base = wr * 64 + mt * 16 + quad * 4;
                uint2 pk;
                pk.x = pack_bf(acc[mt][nt][0] + bn, acc[mt][nt][1] + bn);
                pk.y = pack_bf(acc[mt][nt][2] + bn, acc[mt][nt][3] + bn);
                *(uint2*)(stg + n_local * 136 + m_base) = pk;
            }
        }
        __syncthreads();
        const int n_row = tid >> 1;     // 0..255
        const int half = tid & 1;       // 64-m segment
        const int n = n0 + n_row;
        const int nh = n >> 6, hd = n & 63;
        const uint4* src = (const uint4*)(stg + n_row * 136 + half * 64);
        uint4* dst = (uint4*)(vbT + ((size_t)((bgl << 4) | nh) * HD + hd) * SS
                              + (m0 & 4095) + half * 64);
#pragma unroll
        for (int jj = 0; jj < 8; ++jj) dst[jj] = src[jj];
    }
}

// ---------------- R1 fallback projection (inline convert) ----------------
__global__ __launch_bounds__(256)
void proj3_kernel(const float* __restrict__ Xq, const float* __restrict__ Xk,
                  const float* __restrict__ Xv,
                  const float* __restrict__ Wq, const float* __restrict__ Wk,
                  const float* __restrict__ Wv,
                  const float* __restrict__ bq, const float* __restrict__ bk,
                  const float* __restrict__ bv,
                  ushort* __restrict__ qb, ushort* __restrict__ kb,
                  ushort* __restrict__ vbT)
{
    __shared__ __align__(16) ushort smem[128 * 136];
    ushort* As = smem;             // [128][40]
    ushort* Bs = smem + 128 * 40;  // [128][40]

    const int z = blockIdx.z;
    const float* X    = (z == 0) ? Xq : (z == 1) ? Xk : Xv;
    const float* W    = (z == 0) ? Wq : (z == 1) ? Wk : Wv;
    const float* bias = (z == 0) ? bq : (z == 1) ? bk : bv;

    const int tid = threadIdx.x;
    const int m0 = blockIdx.x * 128;
    const int n0 = blockIdx.y * 128;
    const int wave = tid >> 6;
    const int lane = tid & 63;
    const int l15 = lane & 15;
    const int quad = lane >> 4;
    const int wr = wave >> 1, wc = wave & 1;

    f32x4 acc[4][4];
#pragma unroll
    for (int mt = 0; mt < 4; ++mt)
#pragma unroll
        for (int nt = 0; nt < 4; ++nt) acc[mt][nt] = (f32x4){0.f, 0.f, 0.f, 0.f};

    const int srow = tid >> 1;
    const int shalf = tid & 1;
    const float* xp = X + (size_t)(m0 + srow) * HH + shalf * 16;
    const float* wp = W + (size_t)(n0 + srow) * HH + shalf * 16;
    ushort* asw = As + srow * 40 + shalf * 16;
    ushort* bsw = Bs + srow * 40 + shalf * 16;

    for (int k0 = 0; k0 < HH; k0 += 32) {
        float4 a0 = *(const float4*)(xp + k0);
        float4 a1 = *(const float4*)(xp + k0 + 4);
        float4 a2 = *(const float4*)(xp + k0 + 8);
        float4 a3 = *(const float4*)(xp + k0 + 12);
        float4 b0 = *(const float4*)(wp + k0);
        float4 b1 = *(const float4*)(wp + k0 + 4);
        float4 b2 = *(const float4*)(wp + k0 + 8);
        float4 b3 = *(const float4*)(wp + k0 + 12);
        __syncthreads();
        uint4 pa, pb;
        pa.x = pack_bf(a0.x, a0.y); pa.y = pack_bf(a0.z, a0.w);
        pa.z = pack_bf(a1.x, a1.y); pa.w = pack_bf(a1.z, a1.w);
        *(uint4*)asw = pa;
        pa.x = pack_bf(a2.x, a2.y); pa.y = pack_bf(a2.z, a2.w);
        pa.z = pack_bf(a3.x, a3.y); pa.w = pack_bf(a3.z, a3.w);
        *(uint4*)(asw + 8) = pa;
        pb.x = pack_bf(b0.x, b0.y); pb.y = pack_bf(b0.z, b0.w);
        pb.z = pack_bf(b1.x, b1.y); pb.w = pack_bf(b1.z, b1.w);
        *(uint4*)bsw = pb;
        pb.x = pack_bf(b2.x, b2.y); pb.y = pack_bf(b2.z, b2.w);
        pb.z = pack_bf(b3.x, b3.y); pb.w = pack_bf(b3.z, b3.w);
        *(uint4*)(bsw + 8) = pb;
        __syncthreads();

        bf16x8 af[4], bfr[4];
#pragma unroll
        for (int mt = 0; mt < 4; ++mt)
            af[mt] = *(const bf16x8*)(As + (wr * 64 + mt * 16 + l15) * 40 + quad * 8);
#pragma unroll
        for (int nt = 0; nt < 4; ++nt)
            bfr[nt] = *(const bf16x8*)(Bs + (wc * 64 + nt * 16 + l15) * 40 + quad * 8);
#pragma unroll
        for (int mt = 0; mt < 4; ++mt)
#pragma unroll
            for (int nt = 0; nt < 4; ++nt)
                acc[mt][nt] = __builtin_amdgcn_mfma_f32_16x16x32_bf16(af[mt], bfr[nt], acc[mt][nt], 0, 0, 0);
    }

    if (z < 2) {
        ushort* outp = (z == 0) ? qb : kb;
#pragma unroll
        for (int nt = 0; nt < 4; ++nt) {
            const int n = n0 + wc * 64 + nt * 16 + l15;
            const float bn = bias[n];
            const int nh = n >> 6, hd = n & 63;
#pragma unroll
            for (int mt = 0; mt < 4; ++mt) {
#pragma unroll
                for (int rr = 0; rr < 4; ++rr) {
                    const int m = m0 + wr * 64 + mt * 16 + quad * 4 + rr;
                    const int bgl = m >> 12, s = m & 4095;
                    outp[((size_t)((bgl << 4) | nh) * SS + s) * HD + hd] = f2bf(acc[mt][nt][rr] + bn);
                }
            }
        }
    } else {
        __syncthreads();
        ushort* stg = smem;
#pragma unroll
        for (int nt = 0; nt < 4; ++nt) {
            const int n_local = wc * 64 + nt * 16 + l15;
            const float bn = bias[n0 + n_local];
#pragma unroll
            for (int mt = 0; mt < 4; ++mt) {
                const int m_base = wr * 64 + mt * 16 + quad * 4;
                uint2 pk;
                pk.x = pack_bf(acc[mt][nt][0] + bn, acc[mt][nt][1] + bn);
                pk.y = pack_bf(acc[mt][nt][2] + bn, acc[mt][nt][3] + bn);
                *(uint2*)(stg + n_local * 136 + m_base) = pk;
            }
        }
        __syncthreads();
        const int n_row = tid >> 1;
        const int half = tid & 1;
        const int n = n0 + n_row;
        const int nh = n >> 6, hd = n & 63;
        const int bgl = m0 >> 12;
        const int sbase = (m0 & 4095) + half * 64;
        const uint4* src = (const uint4*)(stg + n_row * 136 + half * 64);
        uint4* dst = (uint4*)(vbT + ((size_t)((bgl << 4) | nh) * HD + hd) * SS + sbase);
#pragma unroll
        for (int j = 0; j < 8; ++j) dst[j] = src[j];
    }
}

// ---------------- block-sparse attention, S^T + dbuf single-barrier ----------------
__global__ __launch_bounds__(256)
void attn_kernel(const ushort* __restrict__ qg, const ushort* __restrict__ kg,
                 const ushort* __restrict__ vTg,
                 const float* __restrict__ mask, const int* __restrict__ rand_attn,
                 float* __restrict__ out, float* __restrict__ partO,
                 float* __restrict__ partML)
{
    __shared__ __align__(16) ushort qs_ps[64][72];      // q staging, then ps (wave-private bands)
    __shared__ __align__(16) ushort ks2[2][2][64][32];  // [buf][k-chunk][kc][d32] (col-swizzled)
    __shared__ __align__(16) ushort vs2[2][2][64][32];  // [buf][kc-chunk][d][kc32] (col-swizzled)
    __shared__ __align__(16) float qm_s[64];
    __shared__ __align__(16) float km_s[2][64];

    const int tid = threadIdx.x;
    const int wid = blockIdx.x;
    const int bh = wid / 78;
    const int r = wid - bh * 78;
    const int b = bh >> 4, h = bh & 15;

    int i, nkb;
    int kbl[8], pfl[8];
    bool dense;
    int part = 0, which = 0;
    if (r < 62) {
        dense = false;
        i = r + 1;
        const int* ra = rand_attn + ((size_t)h * (LL - 2) + (i - 1)) * RR;
        if (i == 1) {
            kbl[0] = 0; kbl[1] = 1; kbl[2] = 2; kbl[3] = LL - 1;
            kbl[4] = ra[0]; kbl[5] = ra[1]; kbl[6] = ra[2]; kbl[7] = 0;
            pfl[0] = pfl[1] = pfl[2] = pfl[3] = 0;
            pfl[4] = pfl[5] = pfl[6] = 1; pfl[7] = 0;
            nkb = 7;
        } else if (i == LL - 2) {
            kbl[0] = 0; kbl[1] = LL - 3; kbl[2] = LL - 2; kbl[3] = LL - 1;
            kbl[4] = ra[0]; kbl[5] = ra[1]; kbl[6] = ra[2]; kbl[7] = 0;
            pfl[0] = pfl[1] = pfl[2] = pfl[3] = 0;
            pfl[4] = pfl[5] = pfl[6] = 1; pfl[7] = 0;
            nkb = 7;
        } else {
            kbl[0] = 0;      pfl[0] = 0;
            kbl[1] = i - 1;  pfl[1] = 1;
            kbl[2] = i;      pfl[2] = 1;
            kbl[3] = i + 1;  pfl[3] = 1;
            kbl[4] = LL - 1; pfl[4] = 0;
            kbl[5] = ra[0]; kbl[6] = ra[1]; kbl[7] = ra[2];
            pfl[5] = pfl[6] = pfl[7] = 1;
            nkb = 8;
        }
    } else {
        dense = true;
        const int r2 = r - 62;
        which = r2 >> 3;
        part = r2 & 7;
        i = which ? (LL - 1) : 0;
        nkb = 8;
#pragma unroll
        for (int j = 0; j < 8; ++j) { kbl[j] = part * 8 + j; pfl[j] = 0; }
    }

    const int lane = tid & 63;
    const int wave = tid >> 6;
    const int l15 = lane & 15;
    const int quad = lane >> 4;
    const int srow = lane >> 2;
    // swizzled 16B-slot for K/V staging: slot ^= (row_in_16 >> 1) & 3
    const int p8s = (((lane & 3) ^ ((srow >> 1) & 3))) * 8;
    const ushort* kgb = kg + (size_t)bh * SS * HD;
    const ushort* vgb = vTg + (size_t)bh * HD * SS;

#define STAGE_KV(kb_, bp)                                                        \
    do {                                                                         \
        const size_t krow = (size_t)((kb_) * BS + wave * 16 + srow) * HD;        \
        async16(kgb + krow + p8s,      &ks2[bp][0][wave * 16][0]);               \
        async16(kgb + krow + 32 + p8s, &ks2[bp][1][wave * 16][0]);               \
        const size_t vrow = (size_t)(wave * 16 + srow) * SS + (kb_) * BS;        \
        async16(vgb + vrow + p8s,      &vs2[bp][0][wave * 16][0]);               \
        async16(vgb + vrow + 32 + p8s, &vs2[bp][1][wave * 16][0]);               \
    } while (0)

    // stage q (scaled by rsd) + masks + first K/V buffer
    {
        const int row = tid >> 2;
        const int c0 = (tid & 3) * 16;
        const ushort* src = qg + ((size_t)bh * SS + i * BS + row) * HD + c0;
        uint4 w0 = *(const uint4*)src;
        uint4 w1 = *(const uint4*)(src + 8);
        *(uint4*)&qs_ps[row][c0] = scale4(w0);
        *(uint4*)&qs_ps[row][c0 + 8] = scale4(w1);
        if (tid < 64) qm_s[tid] = mask[(size_t)b * SS + i * BS + tid];
    }
    STAGE_KV(kbl[0], 0);
    if (tid < 64) km_s[0][tid] = mask[(size_t)b * SS + kbl[0] * BS + tid];
    __syncthreads();  // publish qs, buf0, masks

    // hoist q fragments (B-operand, n=q=wave*16+l15); qs region becomes ps after this
    bf16x8 aq[2];
    aq[0] = *(const bf16x8*)&qs_ps[wave * 16 + l15][quad * 8];
    aq[1] = *(const bf16x8*)&qs_ps[wave * 16 + l15][32 + quad * 8];
    const float qm = qm_s[wave * 16 + l15];

    // swizzled read slot for K/V tiles (same involution as p8s, row_in_16 = l15)
    const int sqz = (quad ^ ((l15 >> 1) & 3)) * 8;

    float mrow = -1e30f, lrow = 0.0f;   // per-lane, q = wave*16 + l15
    f32x4 accO[4];
#pragma unroll
    for (int dt = 0; dt < 4; ++dt) accO[dt] = (f32x4){0.f, 0.f, 0.f, 0.f};

    for (int it = 0; it < nkb; ++it) {
        const int cur = it & 1;
        if (it + 1 < nkb) {
            STAGE_KV(kbl[it + 1], cur ^ 1);   // flies during this iter's compute
            if (tid < 64) km_s[cur ^ 1][tid] = mask[(size_t)b * SS + kbl[it + 1] * BS + tid];
        }
        const int pf = pfl[it];

        // S^T = K . Q^T : A = K rows (m=kc), B = Q rows (n=q)
        f32x4 sc[4];
#pragma unroll
        for (int nt = 0; nt < 4; ++nt) sc[nt] = (f32x4){0.f, 0.f, 0.f, 0.f};
#pragma unroll
        for (int c = 0; c < 2; ++c) {
#pragma unroll
            for (int nt = 0; nt < 4; ++nt) {
                bf16x8 af = *(const bf16x8*)&ks2[cur][c][nt * 16 + l15][sqz];
                sc[nt] = __builtin_amdgcn_mfma_f32_16x16x32_bf16(af, aq[c], sc[nt], 0, 0, 0);
            }
        }

        // penalties: lane holds (q = wave*16+l15, kc = nt*16+quad*4+rr)
        float p[4][4];
        float bm = -1e30f;
#pragma unroll
        for (int nt = 0; nt < 4; ++nt) {
            const float4 km4 = *(const float4*)&km_s[cur][nt * 16 + quad * 4];
            const float kmv[4] = {km4.x, km4.y, km4.z, km4.w};
#pragma unroll
            for (int rr = 0; rr < 4; ++rr) {
                const float pm = pf ? (qm * kmv[rr]) : kmv[rr];
                const float sv = sc[nt][rr] + (1.0f - pm) * PENf;
                p[nt][rr] = sv;
                bm = fmaxf(bm, sv);
            }
        }
        bm = fmaxf(bm, __shfl_xor(bm, 16));
        bm = fmaxf(bm, __shfl_xor(bm, 32));
        // defer-max (T13): only rescale when some row's max grew by > 8
        if (!__all(bm - mrow <= 8.0f)) {
            const float mn = fmaxf(mrow, bm);
            const float alpha = __expf(mrow - mn);
            mrow = mn;
            float a4[4];
#pragma unroll
            for (int rr = 0; rr < 4; ++rr) a4[rr] = __shfl(alpha, quad * 4 + rr, 64);
#pragma unroll
            for (int dt = 0; dt < 4; ++dt) {
#pragma unroll
                for (int rr = 0; rr < 4; ++rr) accO[dt][rr] *= a4[rr];
            }
            lrow *= alpha;
        }
        float ls = 0.0f;
#pragma unroll
        for (int nt = 0; nt < 4; ++nt)
#pragma unroll
            for (int rr = 0; rr < 4; ++rr) {
                p[nt][rr] = __expf(p[nt][rr] - mrow);   // bounded by e^8 when deferred
                ls += p[nt][rr];
            }
        ls += __shfl_xor(ls, 16);
        ls += __shfl_xor(ls, 32);
        lrow += ls;

        // write P (bf16) into wave-private ps rows; b64 stores
#pragma unroll
        for (int nt = 0; nt < 4; ++nt) {
            uint2 pk;
            pk.x = pack_bf(p[nt][0], p[nt][1]);
            pk.y = pack_bf(p[nt][2], p[nt][3]);
            *(uint2*)&qs_ps[wave * 16 + l15][nt * 16 + quad * 4] = pk;
        }

        // PV: A = ps (m=q), B = vs2 (n=d); ps is wave-private -> no barrier
#pragma unroll
        for (int c = 0; c < 2; ++c) {
            bf16x8 ap = *(const bf16x8*)&qs_ps[wave * 16 + l15][c * 32 + quad * 8];
#pragma unroll
            for (int dt = 0; dt < 4; ++dt) {
                bf16x8 bvf = *(const bf16x8*)&vs2[cur][c][dt * 16 + l15][sqz];
                accO[dt] = __builtin_amdgcn_mfma_f32_16x16x32_bf16(ap, bvf, accO[dt], 0, 0, 0);
            }
        }

        if (it + 1 < nkb) __syncthreads();  // publish buf cur^1; protect buf reuse
    }
#undef STAGE_KV

    if (!dense) {
#pragma unroll
        for (int rr = 0; rr < 4; ++rr) {
            const int qloc = quad * 4 + rr;
            const float lq = __shfl(lrow, qloc, 64);
            const float inv = qm_s[wave * 16 + qloc] / lq;
#pragma unroll
            for (int dt = 0; dt < 4; ++dt) {
                const int d = dt * 16 + l15;
                out[((size_t)b * SS + i * BS + wave * 16 + qloc) * HH + h * HD + d] = accO[dt][rr] * inv;
            }
        }
    } else {
        const int slot = (bh * 2 + which) * 8 + part;
        float* po = partO + (size_t)slot * 4096;
#pragma unroll
        for (int rr = 0; rr < 4; ++rr) {
            const int qrow = wave * 16 + quad * 4 + rr;
#pragma unroll
            for (int dt = 0; dt < 4; ++dt) {
                const int d = dt * 16 + l15;
                po[qrow * 64 + d] = accO[dt][rr];
            }
        }
        if (lane < 16) {
            partML[slot * 128 + wave * 16 + lane] = mrow;
            partML[slot * 128 + 64 + wave * 16 + lane] = lrow;
        }
    }
}

// ---------------- combine partials for dense query blocks ----------------
__global__ __launch_bounds__(64)
void combine_kernel(const float* __restrict__ partO, const float* __restrict__ partML,
                    const float* __restrict__ mask, float* __restrict__ out)
{
    const int g4 = blockIdx.x;    // (bh*2 + which) * 4 + row-quarter
    const int g = g4 >> 2;
    const int bh = g >> 1, which = g & 1;
    const int b = bh >> 4, h = bh & 15;
    const int i = which ? (LL - 1) : 0;
    const int t = threadIdx.x;
    const int row = ((g4 & 3) << 4) | (t >> 2);
    const int d0 = (t & 3) * 16;
    const int base = g * 8;

    float mp[8], lp[8];
    float M = -1e30f;
#pragma unroll
    for (int p = 0; p < 8; ++p) {
        mp[p] = partML[(base + p) * 128 + row];
        lp[p] = partML[(base + p) * 128 + 64 + row];
        M = fmaxf(M, mp[p]);
    }
    float L = 0.0f, w[8];
#pragma unroll
    for (int p = 0; p < 8; ++p) { w[p] = __expf(mp[p] - M); L += lp[p] * w[p]; }

    float4 o[4];
#pragma unroll
    for (int j = 0; j < 4; ++j) o[j] = make_float4(0.f, 0.f, 0.f, 0.f);
#pragma unroll
    for (int p = 0; p < 8; ++p) {
        const float* po = partO + (size_t)(base + p) * 4096 + row * 64 + d0;
#pragma unroll
        for (int j = 0; j < 4; ++j) {
            float4 v = *(const float4*)(po + j * 4);
            o[j].x = fmaf(w[p], v.x, o[j].x);
            o[j].y = fmaf(w[p], v.y, o[j].y);
            o[j].z = fmaf(w[p], v.z, o[j].z);
            o[j].w = fmaf(w[p], v.w, o[j].w);
        }
    }
    const float fm = mask[(size_t)b * SS + i * BS + row];
    const float inv = fm / L;
    float* dst = out + ((size_t)b * SS + i * BS + row) * HH + h * HD + d0;
#pragma unroll
    for (int j = 0; j < 4; ++j) {
        float4 v;
        v.x = o[j].x * inv; v.y = o[j].y * inv;
        v.z = o[j].z * inv; v.w = o[j].w * inv;
        *(float4*)(dst + j * 4) = v;
    }
}

extern "C" void kernel_launch(void* const* d_in, const int* in_sizes, int n_in,
                              void* d_out, int out_size, void* d_ws, size_t ws_size,
                              hipStream_t stream) {
    (void)in_sizes; (void)n_in; (void)out_size;
    const float* Q    = (const float*)d_in[0];
    const float* K    = (const float*)d_in[1];
    const float* V    = (const float*)d_in[2];
    const float* mask = (const float*)d_in[3];
    const float* Wq   = (const float*)d_in[4];
    const float* bq   = (const float*)d_in[5];
    const float* Wk   = (const float*)d_in[6];
    const float* bk   = (const float*)d_in[7];
    const float* Wv   = (const float*)d_in[8];
    const float* bv   = (const float*)d_in[9];
    const int*   ra   = (const int*)d_in[10];
    float* out = (float*)d_out;

    const size_t qkv = (size_t)BB * NHh * SS * HD;  // 8388608 elems
    ushort* qb  = (ushort*)d_ws;
    ushort* kb  = qb + qkv;
    ushort* vbT = kb + qkv;
    float* partO  = (float*)(vbT + qkv);            // 512 * 4096 f32
    float* partML = partO + (size_t)512 * 4096;     // 512 * 128 f32
    ushort* Xbf = (ushort*)(partML + (size_t)512 * 128);
    ushort* Wbf = Xbf + 3 * qkv;
    const size_t need = (size_t)((char*)(Wbf + (size_t)3 * HH * HH) - (char*)d_ws);

    if (ws_size >= need) {
        cvt_kernel<<<13824, 256, 0, stream>>>(Q, K, V, Wq, Wk, Wv, Xbf, Wbf);
        gemm6_kernel<<<dim3(64, 4, 3), 512, 0, stream>>>(Xbf, Wbf, bq, bk, bv, qb, kb, vbT);
    } else {
        proj3_kernel<<<dim3(64, 8, 3), 256, 0, stream>>>(Q, K, V, Wq, Wk, Wv, bq, bk, bv,
                                                         qb, kb, vbT);
    }
    attn_kernel<<<dim3(BB * NHh * 78), 256, 0, stream>>>(qb, kb, vbT, mask, ra,
                                                         out, partO, partML);
    combine_kernel<<<dim3(BB * NHh * 2 * 4), 64, 0, stream>>>(partO, partML, mask, out);
}